// Round 1
// 339.819 us; speedup vs baseline: 1.1144x; 1.1144x over previous
//
#include <hip/hip_runtime.h>
#include <hip/hip_bf16.h>

#define N_NODES 50000
#define N_EDGES 800000
#define H 64
#define ED 32
#define LAYERS 3
#define NGRAPH 256
#define OUTD 32
#define SCALE 0.125f

// bucketed counting sort for CSR build (no global atomics anywhere)
#define BNODES 128                                  // nodes per bucket (dst >> 7)
#define NBUCK ((N_NODES + BNODES - 1) / BNODES)     // 391
#define NB_HISTB 128                                // histogram / scatter blocks
#define EPB (N_EDGES / NB_HISTB)                    // 6250 edges per block

// fused front-end block ranges (hist first so CSR chain starts earliest)
#define NB_INIT 12500
#define NB_TE   8
#define NB_GB   2
#define NB_WB   192                                 // 3*256*64 bf16 weight fragments / 256
#define NB_FRONT (NB_HISTB + NB_INIT + NB_TE + NB_GB + NB_WB)
#define NB_GEMM ((N_NODES + 63) / 64)               // 782

typedef __attribute__((ext_vector_type(8))) short bf16x8;
typedef __attribute__((ext_vector_type(4))) float f32x4;
typedef unsigned short ushort_t;

// fp32 -> bf16 round-to-nearest-even
__device__ __forceinline__ unsigned f2bf(float f) {
    unsigned u = __float_as_uint(f);
    return (u + 0x7FFFu + ((u >> 16) & 1u)) >> 16;
}
__device__ __forceinline__ short bfs(float f) { return (short)f2bf(f); }

// ---------------- fused front end: bucket-hist | init_h | te | gbounds | weight-frags ----
__global__ __launch_bounds__(256) void k_front(
    const int* __restrict__ x, const float* __restrict__ node_emb, float* __restrict__ h,
    const float* __restrict__ edge_emb, const float* __restrict__ We, float* __restrict__ te,
    const int* __restrict__ ei, int* __restrict__ hist,
    const int* __restrict__ batch, int* __restrict__ gs,
    const float* __restrict__ Wq, const float* __restrict__ Wk,
    const float* __restrict__ Wv, const float* __restrict__ Wsk,
    ushort_t* __restrict__ wb16)
{
    __shared__ int lh[NBUCK];
    int b = blockIdx.x, t = threadIdx.x;
    if (b < NB_HISTB) {
        // per-block bucket histogram in LDS; streaming writeback
        for (int i = t; i < NBUCK; i += 256) lh[i] = 0;
        __syncthreads();
        const int* dstp = ei + N_EDGES + b * EPB;
        for (int i = t; i < EPB; i += 256)
            atomicAdd(&lh[dstp[i] >> 7], 1);
        __syncthreads();
        for (int i = t; i < NBUCK; i += 256) hist[b * NBUCK + i] = lh[i];
    } else if (b < NB_HISTB + NB_INIT) {
        int i = (b - NB_HISTB) * 256 + t;
        int n = i >> 6, c = i & 63;
        h[i] = node_emb[x[n] * H + c];
    } else if (b < NB_HISTB + NB_INIT + NB_TE) {
        int i = (b - NB_HISTB - NB_INIT) * 256 + t;
        if (i < LAYERS * 10 * H) {
            int c = i & 63;
            int cat = (i >> 6) % 10;
            int l = i / (10 * H);
            float acc = 0.f;
            for (int d = 0; d < ED; d++)
                acc += edge_emb[cat * ED + d] * We[((size_t)l * ED + d) * H + c];
            te[i] = acc;
        }
    } else if (b < NB_HISTB + NB_INIT + NB_TE + NB_GB) {
        int g = (b - NB_HISTB - NB_INIT - NB_TE) * 256 + t;
        if (g <= NGRAPH) {
            int lo = 0, hi = N_NODES;
            while (lo < hi) {
                int mid = (lo + hi) >> 1;
                if (batch[mid] < g) lo = mid + 1; else hi = mid;
            }
            gs[g] = lo;
        }
    } else {
        // bf16 B-fragment layout: wb16[l][c][k], k contiguous (c = mat*64+n)
        int j = (b - NB_HISTB - NB_INIT - NB_TE - NB_GB) * 256 + t;   // < 49152
        int c = j & 255;
        int k = (j >> 8) & 63;
        int l = j >> 14;
        int mat = c >> 6, n = c & 63;
        const float* Wm = (mat == 0) ? Wq : (mat == 1) ? Wk : (mat == 2) ? Wv : Wsk;
        float v = Wm[(size_t)l * 4096 + k * 64 + n];
        wb16[(size_t)l * 16384 + (size_t)c * 64 + k] = (ushort_t)f2bf(v);
    }
}

// ---------------- bucket scan: in-place per-bucket block prefixes + bucket bases -------
__global__ __launch_bounds__(512) void k_scanB(int* __restrict__ hist, int* __restrict__ bstart)
{
    __shared__ int tot[512];
    int t = threadIdx.x;
    int run = 0;
    if (t < NBUCK) {
        #pragma unroll 8
        for (int i = 0; i < NB_HISTB; i++) {
            int v = hist[i * NBUCK + t];
            hist[i * NBUCK + t] = run;   // exclusive prefix across blocks, per bucket
            run += v;
        }
    }
    tot[t] = (t < NBUCK) ? run : 0;
    __syncthreads();
    for (int off = 1; off < 512; off <<= 1) {
        int add = (t >= off) ? tot[t - off] : 0;
        __syncthreads();
        tot[t] += add;
        __syncthreads();
    }
    if (t < NBUCK) bstart[t] = tot[t] - run;         // exclusive bucket base
    if (t == NBUCK - 1) bstart[NBUCK] = tot[t];      // == N_EDGES
}

// ---------------- MFMA gemm body: wave = 16 nodes x 256 outputs ----------------
__device__ __forceinline__ void gemm_mfma_body(
    int bid, const float* __restrict__ h, const ushort_t* __restrict__ wb,
    const float* __restrict__ bq, const float* __restrict__ bk,
    const float* __restrict__ bv, const float* __restrict__ bsk,
    unsigned* __restrict__ qs32, unsigned* __restrict__ kv32)
{
    int tid = threadIdx.x;
    int w = tid >> 6, lane = tid & 63;
    int n16 = lane & 15, quad = lane >> 4;
    int base = bid * 64;
    int nodeA = base + w * 16 + n16;
    const float* hrow = h + (size_t)min(nodeA, N_NODES - 1) * H;
    f32x4 acc[16];
    #pragma unroll
    for (int i = 0; i < 16; i++) acc[i] = (f32x4){0.f, 0.f, 0.f, 0.f};
    #pragma unroll
    for (int kb = 0; kb < 2; kb++) {
        const float* hp = hrow + kb * 32 + quad * 8;
        float4 ha = *(const float4*)hp;
        float4 hb = *(const float4*)(hp + 4);
        bf16x8 afr;
        afr[0] = bfs(ha.x); afr[1] = bfs(ha.y); afr[2] = bfs(ha.z); afr[3] = bfs(ha.w);
        afr[4] = bfs(hb.x); afr[5] = bfs(hb.y); afr[6] = bfs(hb.z); afr[7] = bfs(hb.w);
        #pragma unroll
        for (int ct = 0; ct < 16; ct++) {
            const bf16x8* bp = (const bf16x8*)(wb + ((size_t)(ct * 16 + n16)) * 64 + kb * 32 + quad * 8);
            acc[ct] = __builtin_amdgcn_mfma_f32_16x16x32_bf16(afr, *bp, acc[ct], 0, 0, 0);
        }
    }
    #pragma unroll
    for (int cc = 0; cc < 4; cc++) {
        int col = cc * 16 + n16;
        float bQ = bq[col], bK = bk[col], bV = bv[col], bS = bsk[col];
        #pragma unroll
        for (int r = 0; r < 4; r++) {
            int node = base + w * 16 + quad * 4 + r;
            if (node < N_NODES) {
                float qv = acc[cc][r] + bQ;
                float kk = acc[4 + cc][r] + bK;
                float vv = acc[8 + cc][r] + bV;
                float sv = acc[12 + cc][r] + bS;
                qs32[(size_t)node * 64 + col] = f2bf(qv) | (f2bf(sv) << 16);
                kv32[(size_t)node * 64 + col] = f2bf(vv) | (f2bf(kk) << 16);
            }
        }
    }
}

// layers 1,2: plain gemm
__global__ __launch_bounds__(256, 1) void k_gemm(
    const float* __restrict__ h, const ushort_t* __restrict__ wb,
    const float* __restrict__ bq, const float* __restrict__ bk,
    const float* __restrict__ bv, const float* __restrict__ bsk,
    unsigned* __restrict__ qs32, unsigned* __restrict__ kv32)
{
    gemm_mfma_body(blockIdx.x, h, wb, bq, bk, bv, bsk, qs32, kv32);
}

// layer 0: scatter blocks [0, NB_HISTB), gemm blocks [NB_HISTB, NB_HISTB+NB_GEMM)
// scatter: LDS cursor per bucket, rank via LDS atomic, write packet to bucket region
__global__ __launch_bounds__(256, 1) void k_gemm_scatter(
    const float* __restrict__ h, const ushort_t* __restrict__ wb,
    const float* __restrict__ bq, const float* __restrict__ bk,
    const float* __restrict__ bv, const float* __restrict__ bsk,
    unsigned* __restrict__ qs32, unsigned* __restrict__ kv32,
    const int* __restrict__ ei, const int* __restrict__ ea,
    const int* __restrict__ hist, const int* __restrict__ bstart,
    int* __restrict__ pmid)
{
    __shared__ int cur[NBUCK];
    int b = blockIdx.x, t = threadIdx.x;
    if (b < NB_HISTB) {
        for (int i = t; i < NBUCK; i += 256)
            cur[i] = bstart[i] + hist[b * NBUCK + i];
        __syncthreads();
        int e0 = b * EPB;
        for (int i = t; i < EPB; i += 256) {
            int e = e0 + i;
            int src = ei[e], dst = ei[N_EDGES + e], cat = ea[e];
            int pos = atomicAdd(&cur[dst >> 7], 1);
            pmid[pos] = src | (cat << 16) | ((dst & 127) << 20);
        }
    } else {
        gemm_mfma_body(b - NB_HISTB, h, wb, bq, bk, bv, bsk, qs32, kv32);
    }
}

// ---------------- per-bucket finalize: exact CSR rows + in-bucket ordering -------------
__global__ __launch_bounds__(256) void k_final(
    const int* __restrict__ pmid, const int* __restrict__ bstart,
    int* __restrict__ packed, int* __restrict__ row_start, int* __restrict__ row_end)
{
    __shared__ int cnt[BNODES];
    __shared__ int scan_s[BNODES];
    int b = blockIdx.x, t = threadIdx.x;
    int beg = bstart[b], end = bstart[b + 1];
    if (t < BNODES) cnt[t] = 0;
    __syncthreads();
    for (int e = beg + t; e < end; e += 256)
        atomicAdd(&cnt[(pmid[e] >> 20) & 127], 1);
    __syncthreads();
    if (t < BNODES) scan_s[t] = cnt[t];
    __syncthreads();
    for (int off = 1; off < BNODES; off <<= 1) {
        int add = (t >= off && t < BNODES) ? scan_s[t - off] : 0;
        __syncthreads();
        if (t < BNODES) scan_s[t] += add;
        __syncthreads();
    }
    if (t < BNODES) {
        int c = cnt[t];
        int excl = scan_s[t] - c;          // exclusive within bucket
        int node = b * BNODES + t;
        if (node < N_NODES) {
            row_start[node] = beg + excl;
            row_end[node] = beg + excl + c;
        }
        cnt[t] = beg + excl;               // reuse as cursor
    }
    __syncthreads();
    for (int e = beg + t; e < end; e += 256) {
        int p = pmid[e];
        int pos = atomicAdd(&cnt[(p >> 20) & 127], 1);
        packed[pos] = p & 0xFFFFF;         // src | cat<<16
    }
}

// per-edge load bundle
struct EdgeLd { uint4 kv; float4 t; };
__device__ __forceinline__ EdgeLd edge_load(int pkt, const unsigned* __restrict__ kv32,
                                            const float* tel, int i16) {
    EdgeLd r;
    r.kv = *(const uint4*)(kv32 + ((size_t)(pkt & 0xFFFF) << 6) + (i16 << 2));
    r.t  = *(const float4*)(tel + ((pkt >> 16) << 6) + (i16 << 2));
    return r;
}
__device__ __forceinline__ float edge_dot(const EdgeLd& e, const float4& q4) {
    float p;
    p = (__uint_as_float(e.kv.x & 0xFFFF0000u) + e.t.x) * q4.x;
    p = fmaf(__uint_as_float(e.kv.y & 0xFFFF0000u) + e.t.y, q4.y, p);
    p = fmaf(__uint_as_float(e.kv.z & 0xFFFF0000u) + e.t.z, q4.z, p);
    p = fmaf(__uint_as_float(e.kv.w & 0xFFFF0000u) + e.t.w, q4.w, p);
    p += __shfl_xor(p, 1); p += __shfl_xor(p, 2);
    p += __shfl_xor(p, 4); p += __shfl_xor(p, 8);
    return p * SCALE;
}
__device__ __forceinline__ float4 edge_val(const EdgeLd& e) {
    float4 v;
    v.x = __uint_as_float(e.kv.x << 16) + e.t.x;
    v.y = __uint_as_float(e.kv.y << 16) + e.t.y;
    v.z = __uint_as_float(e.kv.z << 16) + e.t.z;
    v.w = __uint_as_float(e.kv.w << 16) + e.t.w;
    return v;
}

// ---------------- fused gather: one dst per 16-lane group (4 dsts/wave) -------------
__global__ __launch_bounds__(256) void k_agg(
    const int* __restrict__ row_start, const int* __restrict__ row_end,
    const int* __restrict__ packed,
    const unsigned* __restrict__ qs32, const unsigned* __restrict__ kv32,
    const float* __restrict__ te, float* __restrict__ h,
    const float* __restrict__ gW, const float* __restrict__ gb, float* __restrict__ gate)
{
    __shared__ float tel[10 * 64];
    int t = threadIdx.x;
    int wave = t >> 6, lane = t & 63;
    int g = lane >> 4, i16 = lane & 15;
    int dst = blockIdx.x * 16 + wave * 4 + g;
    bool active = dst < N_NODES;
    int beg = 0, end = 0;
    uint4 uq = {0u, 0u, 0u, 0u};
    if (active) {
        beg = row_start[dst];
        end = row_end[dst];
        uq = *(const uint4*)(qs32 + (size_t)dst * 64 + (i16 << 2));   // q lo16 | s hi16, x4 channels
    }
    for (int i = t; i < 10 * 64; i += 256) tel[i] = te[i];
    __syncthreads();
    float4 q4, s4;
    q4.x = __uint_as_float(uq.x << 16); s4.x = __uint_as_float(uq.x & 0xFFFF0000u);
    q4.y = __uint_as_float(uq.y << 16); s4.y = __uint_as_float(uq.y & 0xFFFF0000u);
    q4.z = __uint_as_float(uq.z << 16); s4.z = __uint_as_float(uq.z & 0xFFFF0000u);
    q4.w = __uint_as_float(uq.w << 16); s4.w = __uint_as_float(uq.w & 0xFFFF0000u);
    float m = -1e30f, l = 0.f;
    float4 acc = {0.f, 0.f, 0.f, 0.f};
    int e = beg;
    for (; e + 3 < end; e += 4) {
        int p0 = packed[e], p1 = packed[e + 1], p2 = packed[e + 2], p3 = packed[e + 3];
        EdgeLd e0 = edge_load(p0, kv32, tel, i16);
        EdgeLd e1 = edge_load(p1, kv32, tel, i16);
        EdgeLd e2 = edge_load(p2, kv32, tel, i16);
        EdgeLd e3 = edge_load(p3, kv32, tel, i16);
        float a0 = edge_dot(e0, q4), a1 = edge_dot(e1, q4);
        float a2 = edge_dot(e2, q4), a3 = edge_dot(e3, q4);
        float mn = fmaxf(m, fmaxf(fmaxf(a0, a1), fmaxf(a2, a3)));
        float corr = __expf(m - mn);
        float w0 = __expf(a0 - mn), w1 = __expf(a1 - mn);
        float w2 = __expf(a2 - mn), w3 = __expf(a3 - mn);
        float4 v0 = edge_val(e0), v1 = edge_val(e1), v2 = edge_val(e2), v3 = edge_val(e3);
        acc.x = fmaf(w0, v0.x, fmaf(w1, v1.x, fmaf(w2, v2.x, fmaf(w3, v3.x, acc.x * corr))));
        acc.y = fmaf(w0, v0.y, fmaf(w1, v1.y, fmaf(w2, v2.y, fmaf(w3, v3.y, acc.y * corr))));
        acc.z = fmaf(w0, v0.z, fmaf(w1, v1.z, fmaf(w2, v2.z, fmaf(w3, v3.z, acc.z * corr))));
        acc.w = fmaf(w0, v0.w, fmaf(w1, v1.w, fmaf(w2, v2.w, fmaf(w3, v3.w, acc.w * corr))));
        l = fmaf(l, corr, (w0 + w1) + (w2 + w3));
        m = mn;
    }
    for (; e < end; e++) {
        int pkt = packed[e];
        EdgeLd e0 = edge_load(pkt, kv32, tel, i16);
        float a = edge_dot(e0, q4);
        float mn = fmaxf(m, a);
        float corr = __expf(m - mn);
        float w = __expf(a - mn);
        float4 v4 = edge_val(e0);
        acc.x = fmaf(w, v4.x, acc.x * corr);
        acc.y = fmaf(w, v4.y, acc.y * corr);
        acc.z = fmaf(w, v4.z, acc.z * corr);
        acc.w = fmaf(w, v4.w, acc.w * corr);
        l = fmaf(l, corr, w);
        m = mn;
    }
    float inv = (l > 0.f) ? 1.f / l : 0.f;
    float4 hv;
    hv.x = fmaxf(acc.x * inv + s4.x, 0.f);
    hv.y = fmaxf(acc.y * inv + s4.y, 0.f);
    hv.z = fmaxf(acc.z * inv + s4.z, 0.f);
    hv.w = fmaxf(acc.w * inv + s4.w, 0.f);
    if (active) *(float4*)(h + (size_t)dst * H + (i16 << 2)) = hv;
    if (gW && active) {
        float4 g4 = *(const float4*)(gW + (i16 << 2));
        float p = hv.x * g4.x + hv.y * g4.y + hv.z * g4.z + hv.w * g4.w;
        p += __shfl_xor(p, 1); p += __shfl_xor(p, 2);
        p += __shfl_xor(p, 4); p += __shfl_xor(p, 8);
        if (i16 == 0) gate[dst] = p + gb[0];
    }
}

// ---------------- fused per-graph readout ----------------
__global__ __launch_bounds__(256) void k_readout2(
    const float* __restrict__ h, const float* __restrict__ oW,
    const float* __restrict__ ob, const float* __restrict__ gate,
    const int* __restrict__ gs, float* __restrict__ out)
{
    __shared__ float wls[H * OUTD];
    __shared__ float hs[8][H + 1];
    __shared__ float red[256];
    __shared__ float den_s[8];
    __shared__ float gmax_s, den_tot;
    int t = threadIdx.x;
    int g = blockIdx.x;
    for (int i = t; i < H * OUTD; i += 256) wls[i] = oW[i];
    int beg = gs[g], end = gs[g + 1];
    float mx = -INFINITY;
    for (int n = beg + t; n < end; n += 256) mx = fmaxf(mx, gate[n]);
    red[t] = mx;
    __syncthreads();
    for (int sft = 128; sft > 0; sft >>= 1) {
        if (t < sft) red[t] = fmaxf(red[t], red[t + sft]);
        __syncthreads();
    }
    if (t == 0) gmax_s = red[0];
    __syncthreads();
    float gm = gmax_s;
    int ln = t >> 5, o = t & 31;
    float acc = 0.f, den = 0.f;
    for (int n0 = beg; n0 < end; n0 += 8) {
        __syncthreads();
        for (int i = t; i < 8 * H; i += 256) {
            int r = i >> 6, c = i & 63;
            int n = n0 + r;
            hs[r][c] = (n < end) ? h[(size_t)n * H + c] : 0.f;
        }
        __syncthreads();
        int n = n0 + ln;
        if (n < end) {
            float wt = __expf(gate[n] - gm);
            float d0 = 0.f;
            #pragma unroll
            for (int i = 0; i < H; i++) d0 += hs[ln][i] * wls[i * OUTD + o];
            acc += wt * d0;
            if (o == 0) den += wt;
        }
    }
    __syncthreads();
    red[t] = acc;
    if (o == 0) den_s[ln] = den;
    __syncthreads();
    for (int sft = 4; sft >= 1; sft >>= 1) {
        if (ln < sft) red[t] += red[t + sft * 32];
        __syncthreads();
    }
    if (t == 0) {
        float dt = 0.f;
        #pragma unroll
        for (int i = 0; i < 8; i++) dt += den_s[i];
        den_tot = dt;
    }
    __syncthreads();
    if (ln == 0) {
        float dt = den_tot;
        out[g * OUTD + o] = (dt > 0.f) ? red[o] / dt + ob[o] : 0.f;
    }
}

extern "C" void kernel_launch(void* const* d_in, const int* in_sizes, int n_in,
                              void* d_out, int out_size, void* d_ws, size_t ws_size,
                              hipStream_t stream)
{
    const int* x        = (const int*)d_in[0];
    const int* ei       = (const int*)d_in[1];
    const int* ea       = (const int*)d_in[2];
    const int* batch    = (const int*)d_in[3];
    const float* node_emb = (const float*)d_in[4];
    const float* edge_emb = (const float*)d_in[5];
    const float* Wq    = (const float*)d_in[6];
    const float* Wk    = (const float*)d_in[7];
    const float* Wv    = (const float*)d_in[8];
    const float* We    = (const float*)d_in[9];
    const float* Wskip = (const float*)d_in[10];
    const float* bq    = (const float*)d_in[11];
    const float* bk    = (const float*)d_in[12];
    const float* bv    = (const float*)d_in[13];
    const float* bskip = (const float*)d_in[14];
    const float* gate_W = (const float*)d_in[15];
    const float* gate_b = (const float*)d_in[16];
    const float* out_W  = (const float*)d_in[17];
    const float* out_b  = (const float*)d_in[18];
    float* out = (float*)d_out;

    const size_t NH = (size_t)N_NODES * H;
    float* ws   = (float*)d_ws;
    float* h    = ws;                          // fp32 h, NH floats
    unsigned* qs32 = (unsigned*)(h + NH);      // q|s packed bf16, 64 dwords/node
    unsigned* kv32 = (unsigned*)(h + 2 * NH);  // v|k packed bf16, 64 dwords/node
    float* te   = h + 3 * NH;
    float* gate = te + LAYERS * 10 * H;
    int* row_start = (int*)(gate + N_NODES);
    int* row_end   = row_start + N_NODES;
    int* packed    = row_end + N_NODES;        // final CSR edge packets
    int* pmid      = packed + N_EDGES;         // bucket-sorted intermediate
    int* hist      = pmid + N_EDGES;           // NB_HISTB * NBUCK
    int* bstart    = hist + NB_HISTB * NBUCK;  // NBUCK + 1
    int* gs        = bstart + NBUCK + 1;       // 257 ints
    ushort_t* wb16 = (ushort_t*)(gs + NGRAPH + 1);  // 3*16384 bf16 weight fragments

    k_front<<<NB_FRONT, 256, 0, stream>>>(x, node_emb, h, edge_emb, We, te, ei, hist, batch, gs,
                                          Wq, Wk, Wv, Wskip, wb16);
    k_scanB<<<1, 512, 0, stream>>>(hist, bstart);

    // layer 0: bucket scatter (blocks 0..127) co-scheduled with MFMA gemm
    k_gemm_scatter<<<NB_HISTB + NB_GEMM, 256, 0, stream>>>(
        h, wb16, bq, bk, bv, bskip, qs32, kv32, ei, ea, hist, bstart, pmid);
    k_final<<<NBUCK, 256, 0, stream>>>(pmid, bstart, packed, row_start, row_end);
    k_agg<<<(N_NODES + 15) / 16, 256, 0, stream>>>(
        row_start, row_end, packed, qs32, kv32, te, h, nullptr, nullptr, nullptr);

    for (int l = 1; l < LAYERS; l++) {
        k_gemm<<<NB_GEMM, 256, 0, stream>>>(
            h, wb16 + (size_t)l * 16384,
            bq + (size_t)l * H, bk + (size_t)l * H, bv + (size_t)l * H, bskip + (size_t)l * H,
            qs32, kv32);
        const float* gw = (l == LAYERS - 1) ? gate_W : nullptr;
        const float* gb = (l == LAYERS - 1) ? gate_b : nullptr;
        float* gp       = (l == LAYERS - 1) ? gate : nullptr;
        k_agg<<<(N_NODES + 15) / 16, 256, 0, stream>>>(
            row_start, row_end, packed, qs32, kv32, te + (size_t)l * 10 * H, h, gw, gb, gp);
    }

    k_readout2<<<NGRAPH, 256, 0, stream>>>(h, out_W, out_b, gate, gs, out);
}

// Round 2
// 326.038 us; speedup vs baseline: 1.1615x; 1.0423x over previous
//
#include <hip/hip_runtime.h>
#include <hip/hip_bf16.h>

#define N_NODES 50000
#define N_EDGES 800000
#define H 64
#define ED 32
#define LAYERS 3
#define NGRAPH 256
#define OUTD 32
#define SCALE 0.125f

// bucketed counting sort for CSR build (no global atomics anywhere)
#define BNODES 128                                  // nodes per bucket (dst >> 7)
#define NBUCK ((N_NODES + BNODES - 1) / BNODES)     // 391
#define NB_HISTB 128                                // histogram / scatter blocks
#define EPB (N_EDGES / NB_HISTB)                    // 6250 edges per block

// fused front-end block ranges (hist first so CSR chain starts earliest)
#define NB_INIT 1563                                // 50000*64/8 bf16x8 writes / 256
#define NB_TE   8
#define NB_GB   2
#define NB_WB   192                                 // 3*16384 bf16 weight fragments / 256
#define NB_FRONT (NB_HISTB + NB_INIT + NB_TE + NB_GB + NB_WB)
#define NB_GEMM ((N_NODES + 63) / 64)               // 782

typedef __attribute__((ext_vector_type(8))) short bf16x8;
typedef __attribute__((ext_vector_type(4))) float f32x4;
typedef unsigned short ushort_t;

// fp32 -> bf16 round-to-nearest-even
__device__ __forceinline__ unsigned f2bf(float f) {
    unsigned u = __float_as_uint(f);
    return (u + 0x7FFFu + ((u >> 16) & 1u)) >> 16;
}

// 16-lane all-reduce sum via DPP (VALU only, no LDS pipe).
// quad butterfly (xor1, xor2) then row_ror:4 + row_ror:8 — every lane gets the
// full 16-lane sum. Groups are 16-lane aligned => DPP rows never cross groups.
__device__ __forceinline__ float radd16(float x) {
    x += __int_as_float(__builtin_amdgcn_update_dpp(0, __float_as_int(x), 0xB1, 0xF, 0xF, true));   // quad_perm 1,0,3,2
    x += __int_as_float(__builtin_amdgcn_update_dpp(0, __float_as_int(x), 0x4E, 0xF, 0xF, true));   // quad_perm 2,3,0,1
    x += __int_as_float(__builtin_amdgcn_update_dpp(0, __float_as_int(x), 0x124, 0xF, 0xF, true));  // row_ror:4
    x += __int_as_float(__builtin_amdgcn_update_dpp(0, __float_as_int(x), 0x128, 0xF, 0xF, true));  // row_ror:8
    return x;
}

// ---------------- fused front end: bucket-hist | init_hb16 | te | gbounds | weights ----
__global__ __launch_bounds__(256) void k_front(
    const int* __restrict__ x, const float* __restrict__ node_emb, ushort_t* __restrict__ hb16,
    const float* __restrict__ edge_emb, const float* __restrict__ We, float* __restrict__ te,
    const int* __restrict__ ei, int* __restrict__ hist,
    const int* __restrict__ batch, int* __restrict__ gs,
    const float* __restrict__ Wq, const float* __restrict__ Wk,
    const float* __restrict__ Wv, const float* __restrict__ Wsk,
    ushort_t* __restrict__ wb16)
{
    __shared__ int lh[NBUCK];
    int b = blockIdx.x, t = threadIdx.x;
    if (b < NB_HISTB) {
        // per-block bucket histogram in LDS; transposed writeback hist[bucket][block]
        for (int i = t; i < NBUCK; i += 256) lh[i] = 0;
        __syncthreads();
        const int* dstp = ei + N_EDGES + b * EPB;
        for (int i = t; i < EPB; i += 256)
            atomicAdd(&lh[dstp[i] >> 7], 1);
        __syncthreads();
        for (int i = t; i < NBUCK; i += 256) hist[i * NB_HISTB + b] = lh[i];
    } else if (b < NB_HISTB + NB_INIT) {
        int i = (b - NB_HISTB) * 256 + t;
        if (i < N_NODES * 8) {
            int n = i >> 3, c8 = i & 7;
            const float* er = node_emb + (size_t)x[n] * H + c8 * 8;
            float4 f0 = *(const float4*)er;
            float4 f1 = *(const float4*)(er + 4);
            uint4 o;
            o.x = f2bf(f0.x) | (f2bf(f0.y) << 16);
            o.y = f2bf(f0.z) | (f2bf(f0.w) << 16);
            o.z = f2bf(f1.x) | (f2bf(f1.y) << 16);
            o.w = f2bf(f1.z) | (f2bf(f1.w) << 16);
            *(uint4*)(hb16 + (size_t)n * H + c8 * 8) = o;
        }
    } else if (b < NB_HISTB + NB_INIT + NB_TE) {
        int i = (b - NB_HISTB - NB_INIT) * 256 + t;
        if (i < LAYERS * 10 * H) {
            int c = i & 63;
            int cat = (i >> 6) % 10;
            int l = i / (10 * H);
            float acc = 0.f;
            for (int d = 0; d < ED; d++)
                acc += edge_emb[cat * ED + d] * We[((size_t)l * ED + d) * H + c];
            te[i] = acc;
        }
    } else if (b < NB_HISTB + NB_INIT + NB_TE + NB_GB) {
        int g = (b - NB_HISTB - NB_INIT - NB_TE) * 256 + t;
        if (g <= NGRAPH) {
            int lo = 0, hi = N_NODES;
            while (lo < hi) {
                int mid = (lo + hi) >> 1;
                if (batch[mid] < g) lo = mid + 1; else hi = mid;
            }
            gs[g] = lo;
        }
    } else {
        // chunk-major weight layout for conflict-free ds_read_b128:
        // wb16[l][c_id][r][j]  (c_id = kb*4+quad in [0,8), r = ct*16+n16 in [0,256), j in [0,8))
        // element = Wm[k*64+n] with k = (c_id>>2)*32 + (c_id&3)*8 + j, mat = r>>6, n = r&63
        int g = (b - NB_HISTB - NB_INIT - NB_TE - NB_GB) * 256 + t;   // < 49152
        int l = g >> 14;
        int rem = g & 16383;
        int c_id = rem >> 11;
        int rr = (rem >> 3) & 255;
        int j = rem & 7;
        int mat = rr >> 6, n = rr & 63;
        int k = ((c_id >> 2) << 5) + ((c_id & 3) << 3) + j;
        const float* Wm = (mat == 0) ? Wq : (mat == 1) ? Wk : (mat == 2) ? Wv : Wsk;
        wb16[g] = (ushort_t)f2bf(Wm[(size_t)l * 4096 + k * 64 + n]);
    }
}

// ---------------- MFMA gemm body: wave = 16 nodes x 256 outputs ----------------
// A from bf16 h (direct bf16x8 load); B staged in LDS (chunk-major, conflict-free).
__device__ __forceinline__ void gemm_mfma_body(
    int bid, const ushort_t* __restrict__ hb, const ushort_t* __restrict__ wb,
    ushort_t* wlds,
    const float* __restrict__ bq, const float* __restrict__ bk,
    const float* __restrict__ bv, const float* __restrict__ bsk,
    unsigned* __restrict__ qs32, unsigned* __restrict__ kv32)
{
    int tid = threadIdx.x;
    {   // stage the layer's 32 KB weight block: 2048 uint4 / 256 threads = 8 each
        const uint4* s4 = (const uint4*)wb;
        uint4* d4 = (uint4*)wlds;
        #pragma unroll
        for (int it = 0; it < 8; it++) d4[it * 256 + tid] = s4[it * 256 + tid];
    }
    __syncthreads();
    int w = tid >> 6, lane = tid & 63;
    int n16 = lane & 15, quad = lane >> 4;
    int base = bid * 64;
    int nodeA = min(base + w * 16 + n16, N_NODES - 1);
    const ushort_t* hrow = hb + (size_t)nodeA * H;
    f32x4 acc[16];
    #pragma unroll
    for (int i = 0; i < 16; i++) acc[i] = (f32x4){0.f, 0.f, 0.f, 0.f};
    #pragma unroll
    for (int kb = 0; kb < 2; kb++) {
        bf16x8 afr = *(const bf16x8*)(hrow + kb * 32 + quad * 8);
        #pragma unroll
        for (int ct = 0; ct < 16; ct++) {
            const bf16x8* bp = (const bf16x8*)(wlds + (((kb * 4 + quad) << 11) + ((ct * 16 + n16) << 3)));
            acc[ct] = __builtin_amdgcn_mfma_f32_16x16x32_bf16(afr, *bp, acc[ct], 0, 0, 0);
        }
    }
    #pragma unroll
    for (int cc = 0; cc < 4; cc++) {
        int col = cc * 16 + n16;
        float bQ = bq[col], bK = bk[col], bV = bv[col], bS = bsk[col];
        #pragma unroll
        for (int r = 0; r < 4; r++) {
            int node = base + w * 16 + quad * 4 + r;
            if (node < N_NODES) {
                float qv = acc[cc][r] + bQ;
                float kk = acc[4 + cc][r] + bK;
                float vv = acc[8 + cc][r] + bV;
                float sv = acc[12 + cc][r] + bS;
                qs32[(size_t)node * 64 + col] = f2bf(qv) | (f2bf(sv) << 16);
                kv32[(size_t)node * 64 + col] = f2bf(vv) | (f2bf(kk) << 16);
            }
        }
    }
}

// layers 1,2: plain gemm
__global__ __launch_bounds__(256, 1) void k_gemm(
    const ushort_t* __restrict__ hb, const ushort_t* __restrict__ wb,
    const float* __restrict__ bq, const float* __restrict__ bk,
    const float* __restrict__ bv, const float* __restrict__ bsk,
    unsigned* __restrict__ qs32, unsigned* __restrict__ kv32)
{
    __shared__ __align__(16) char smem[32768];
    gemm_mfma_body(blockIdx.x, hb, wb, (ushort_t*)smem, bq, bk, bv, bsk, qs32, kv32);
}

// layer 0: scatter blocks [0, NB_HISTB) build cursors in-block (scanB folded in),
// gemm blocks [NB_HISTB, NB_HISTB+NB_GEMM)
__global__ __launch_bounds__(256, 1) void k_gemm_scatter(
    const ushort_t* __restrict__ hb, const ushort_t* __restrict__ wb,
    const float* __restrict__ bq, const float* __restrict__ bk,
    const float* __restrict__ bv, const float* __restrict__ bsk,
    unsigned* __restrict__ qs32, unsigned* __restrict__ kv32,
    const int* __restrict__ ei, const int* __restrict__ ea,
    const int* __restrict__ hist, int* __restrict__ bstart,
    int* __restrict__ pmid)
{
    __shared__ __align__(16) char smem[32768];
    int b = blockIdx.x, t = threadIdx.x;
    if (b < NB_HISTB) {
        int* curS = (int*)smem;           // NBUCK
        int* totS = curS + 392;           // NBUCK
        int* preS = totS + 392;           // NBUCK
        int* part = preS + 392;           // 256
        int wave = t >> 6, lane = t & 63;
        // per-bucket total + prefix(before my block) from transposed hist, coalesced
        for (int u = wave; u < NBUCK; u += 4) {
            int v0 = hist[u * NB_HISTB + lane];
            int v1 = hist[u * NB_HISTB + 64 + lane];
            int tot = v0 + v1;
            int pre = (lane < b ? v0 : 0) + (64 + lane < b ? v1 : 0);
            #pragma unroll
            for (int m = 1; m < 64; m <<= 1) {
                tot += __shfl_xor(tot, m);
                pre += __shfl_xor(pre, m);
            }
            if (lane == 0) { totS[u] = tot; preS[u] = pre; }
        }
        __syncthreads();
        // exclusive scan of totS over buckets (2 per thread + 256-scan)
        int u0 = t * 2, u1 = t * 2 + 1;
        int a0 = (u0 < NBUCK) ? totS[u0] : 0;
        int a1 = (u1 < NBUCK) ? totS[u1] : 0;
        part[t] = a0 + a1;
        __syncthreads();
        for (int off = 1; off < 256; off <<= 1) {
            int add = (t >= off) ? part[t - off] : 0;
            __syncthreads();
            part[t] += add;
            __syncthreads();
        }
        int excl = part[t] - (a0 + a1);
        if (u0 < NBUCK) { curS[u0] = excl + preS[u0]; if (b == 0) bstart[u0] = excl; }
        if (u1 < NBUCK) { curS[u1] = excl + a0 + preS[u1]; if (b == 0) bstart[u1] = excl + a0; }
        if (b == 0 && t == 0) bstart[NBUCK] = N_EDGES;
        __syncthreads();
        // rank + scatter via LDS atomics
        int e0 = b * EPB;
        for (int i = t; i < EPB; i += 256) {
            int e = e0 + i;
            int src = ei[e], dst = ei[N_EDGES + e], cat = ea[e];
            int pos = atomicAdd(&curS[dst >> 7], 1);
            pmid[pos] = src | (cat << 16) | ((dst & 127) << 20);
        }
    } else {
        gemm_mfma_body(b - NB_HISTB, hb, wb, (ushort_t*)smem, bq, bk, bv, bsk, qs32, kv32);
    }
}

// ---------------- per-bucket finalize: exact CSR rows + in-bucket ordering -------------
__global__ __launch_bounds__(256) void k_final(
    const int* __restrict__ pmid, const int* __restrict__ bstart,
    int* __restrict__ packed, int* __restrict__ row_start, int* __restrict__ row_end)
{
    __shared__ int cnt[BNODES];
    __shared__ int scan_s[BNODES];
    int b = blockIdx.x, t = threadIdx.x;
    int beg = bstart[b], end = bstart[b + 1];
    if (t < BNODES) cnt[t] = 0;
    __syncthreads();
    for (int e = beg + t; e < end; e += 256)
        atomicAdd(&cnt[(pmid[e] >> 20) & 127], 1);
    __syncthreads();
    if (t < BNODES) scan_s[t] = cnt[t];
    __syncthreads();
    for (int off = 1; off < BNODES; off <<= 1) {
        int add = (t >= off && t < BNODES) ? scan_s[t - off] : 0;
        __syncthreads();
        if (t < BNODES) scan_s[t] += add;
        __syncthreads();
    }
    if (t < BNODES) {
        int c = cnt[t];
        int excl = scan_s[t] - c;          // exclusive within bucket
        int node = b * BNODES + t;
        if (node < N_NODES) {
            row_start[node] = beg + excl;
            row_end[node] = beg + excl + c;
        }
        cnt[t] = beg + excl;               // reuse as cursor
    }
    __syncthreads();
    for (int e = beg + t; e < end; e += 256) {
        int p = pmid[e];
        int pos = atomicAdd(&cnt[(p >> 20) & 127], 1);
        packed[pos] = p & 0xFFFFF;         // src | cat<<16
    }
}

// per-edge load bundle
struct EdgeLd { uint4 kv; float4 t; };
__device__ __forceinline__ EdgeLd edge_load(int pkt, const unsigned* __restrict__ kv32,
                                            const float* tel, int i16) {
    EdgeLd r;
    r.kv = *(const uint4*)(kv32 + ((size_t)(pkt & 0xFFFF) << 6) + (i16 << 2));
    r.t  = *(const float4*)(tel + ((pkt >> 16) << 6) + (i16 << 2));
    return r;
}
__device__ __forceinline__ float edge_dot(const EdgeLd& e, const float4& q4) {
    float p;
    p = (__uint_as_float(e.kv.x & 0xFFFF0000u) + e.t.x) * q4.x;
    p = fmaf(__uint_as_float(e.kv.y & 0xFFFF0000u) + e.t.y, q4.y, p);
    p = fmaf(__uint_as_float(e.kv.z & 0xFFFF0000u) + e.t.z, q4.z, p);
    p = fmaf(__uint_as_float(e.kv.w & 0xFFFF0000u) + e.t.w, q4.w, p);
    return radd16(p) * SCALE;
}
__device__ __forceinline__ float4 edge_val(const EdgeLd& e) {
    float4 v;
    v.x = __uint_as_float(e.kv.x << 16) + e.t.x;
    v.y = __uint_as_float(e.kv.y << 16) + e.t.y;
    v.z = __uint_as_float(e.kv.z << 16) + e.t.z;
    v.w = __uint_as_float(e.kv.w << 16) + e.t.w;
    return v;
}

// ---------------- fused gather: one dst per 16-lane group (4 dsts/wave) -------------
// layers 0,1: write bf16 h (hbo != null); layer 2: write fp32 h + gate
__global__ __launch_bounds__(256) void k_agg(
    const int* __restrict__ row_start, const int* __restrict__ row_end,
    const int* __restrict__ packed,
    const unsigned* __restrict__ qs32, const unsigned* __restrict__ kv32,
    const float* __restrict__ te, float* __restrict__ hf, ushort_t* __restrict__ hbo,
    const float* __restrict__ gW, const float* __restrict__ gb, float* __restrict__ gate)
{
    __shared__ float tel[10 * 64];
    int t = threadIdx.x;
    int wave = t >> 6, lane = t & 63;
    int g = lane >> 4, i16 = lane & 15;
    int dst = blockIdx.x * 16 + wave * 4 + g;
    bool active = dst < N_NODES;
    int beg = 0, end = 0;
    uint4 uq = {0u, 0u, 0u, 0u};
    if (active) {
        beg = row_start[dst];
        end = row_end[dst];
        uq = *(const uint4*)(qs32 + (size_t)dst * 64 + (i16 << 2));   // q lo16 | s hi16, x4 channels
    }
    for (int i = t; i < 10 * 64; i += 256) tel[i] = te[i];
    __syncthreads();
    float4 q4, s4;
    q4.x = __uint_as_float(uq.x << 16); s4.x = __uint_as_float(uq.x & 0xFFFF0000u);
    q4.y = __uint_as_float(uq.y << 16); s4.y = __uint_as_float(uq.y & 0xFFFF0000u);
    q4.z = __uint_as_float(uq.z << 16); s4.z = __uint_as_float(uq.z & 0xFFFF0000u);
    q4.w = __uint_as_float(uq.w << 16); s4.w = __uint_as_float(uq.w & 0xFFFF0000u);
    float m = -1e30f, l = 0.f;
    float4 acc = {0.f, 0.f, 0.f, 0.f};
    int e = beg;
    for (; e + 3 < end; e += 4) {
        int p0 = packed[e], p1 = packed[e + 1], p2 = packed[e + 2], p3 = packed[e + 3];
        EdgeLd e0 = edge_load(p0, kv32, tel, i16);
        EdgeLd e1 = edge_load(p1, kv32, tel, i16);
        EdgeLd e2 = edge_load(p2, kv32, tel, i16);
        EdgeLd e3 = edge_load(p3, kv32, tel, i16);
        float a0 = edge_dot(e0, q4), a1 = edge_dot(e1, q4);
        float a2 = edge_dot(e2, q4), a3 = edge_dot(e3, q4);
        float mn = fmaxf(m, fmaxf(fmaxf(a0, a1), fmaxf(a2, a3)));
        float corr = __expf(m - mn);
        float w0 = __expf(a0 - mn), w1 = __expf(a1 - mn);
        float w2 = __expf(a2 - mn), w3 = __expf(a3 - mn);
        float4 v0 = edge_val(e0), v1 = edge_val(e1), v2 = edge_val(e2), v3 = edge_val(e3);
        acc.x = fmaf(w0, v0.x, fmaf(w1, v1.x, fmaf(w2, v2.x, fmaf(w3, v3.x, acc.x * corr))));
        acc.y = fmaf(w0, v0.y, fmaf(w1, v1.y, fmaf(w2, v2.y, fmaf(w3, v3.y, acc.y * corr))));
        acc.z = fmaf(w0, v0.z, fmaf(w1, v1.z, fmaf(w2, v2.z, fmaf(w3, v3.z, acc.z * corr))));
        acc.w = fmaf(w0, v0.w, fmaf(w1, v1.w, fmaf(w2, v2.w, fmaf(w3, v3.w, acc.w * corr))));
        l = fmaf(l, corr, (w0 + w1) + (w2 + w3));
        m = mn;
    }
    for (; e < end; e++) {
        int pkt = packed[e];
        EdgeLd e0 = edge_load(pkt, kv32, tel, i16);
        float a = edge_dot(e0, q4);
        float mn = fmaxf(m, a);
        float corr = __expf(m - mn);
        float w = __expf(a - mn);
        float4 v4 = edge_val(e0);
        acc.x = fmaf(w, v4.x, acc.x * corr);
        acc.y = fmaf(w, v4.y, acc.y * corr);
        acc.z = fmaf(w, v4.z, acc.z * corr);
        acc.w = fmaf(w, v4.w, acc.w * corr);
        l = fmaf(l, corr, w);
        m = mn;
    }
    float inv = (l > 0.f) ? 1.f / l : 0.f;
    float4 hv;
    hv.x = fmaxf(acc.x * inv + s4.x, 0.f);
    hv.y = fmaxf(acc.y * inv + s4.y, 0.f);
    hv.z = fmaxf(acc.z * inv + s4.z, 0.f);
    hv.w = fmaxf(acc.w * inv + s4.w, 0.f);
    if (active) {
        if (hbo) {
            uint2 o;
            o.x = f2bf(hv.x) | (f2bf(hv.y) << 16);
            o.y = f2bf(hv.z) | (f2bf(hv.w) << 16);
            *(uint2*)(hbo + (size_t)dst * H + (i16 << 2)) = o;
        } else {
            *(float4*)(hf + (size_t)dst * H + (i16 << 2)) = hv;
        }
    }
    if (gW && active) {
        float4 g4 = *(const float4*)(gW + (i16 << 2));
        float p = hv.x * g4.x + hv.y * g4.y + hv.z * g4.z + hv.w * g4.w;
        p = radd16(p);
        if (i16 == 0) gate[dst] = p + gb[0];
    }
}

// ---------------- fused per-graph readout (W column in registers) ----------------
__global__ __launch_bounds__(256) void k_readout2(
    const float* __restrict__ h, const float* __restrict__ oW,
    const float* __restrict__ ob, const float* __restrict__ gate,
    const int* __restrict__ gs, float* __restrict__ out)
{
    __shared__ float hs[8][H + 1];
    __shared__ float red[256];
    __shared__ float den_s[8];
    __shared__ float gmax_s, den_tot;
    int t = threadIdx.x;
    int g = blockIdx.x;
    int ln = t >> 5, o = t & 31;
    float wreg[H];
    #pragma unroll
    for (int i = 0; i < H; i++) wreg[i] = oW[i * OUTD + o];
    int beg = gs[g], end = gs[g + 1];
    float mx = -INFINITY;
    for (int n = beg + t; n < end; n += 256) mx = fmaxf(mx, gate[n]);
    red[t] = mx;
    __syncthreads();
    for (int sft = 128; sft > 0; sft >>= 1) {
        if (t < sft) red[t] = fmaxf(red[t], red[t + sft]);
        __syncthreads();
    }
    if (t == 0) gmax_s = red[0];
    __syncthreads();
    float gm = gmax_s;
    float acc = 0.f, den = 0.f;
    for (int n0 = beg; n0 < end; n0 += 8) {
        __syncthreads();
        for (int i = t; i < 8 * H; i += 256) {
            int r = i >> 6, c = i & 63;
            int n = n0 + r;
            hs[r][c] = (n < end) ? h[(size_t)n * H + c] : 0.f;
        }
        __syncthreads();
        int n = n0 + ln;
        if (n < end) {
            float wt = __expf(gate[n] - gm);
            float d0 = 0.f;
            #pragma unroll
            for (int i = 0; i < H; i++) d0 += hs[ln][i] * wreg[i];
            acc += wt * d0;
            if (o == 0) den += wt;
        }
    }
    __syncthreads();
    red[t] = acc;
    if (o == 0) den_s[ln] = den;
    __syncthreads();
    for (int sft = 4; sft >= 1; sft >>= 1) {
        if (ln < sft) red[t] += red[t + sft * 32];
        __syncthreads();
    }
    if (t == 0) {
        float dt = 0.f;
        #pragma unroll
        for (int i = 0; i < 8; i++) dt += den_s[i];
        den_tot = dt;
    }
    __syncthreads();
    if (ln == 0) {
        float dt = den_tot;
        out[g * OUTD + o] = (dt > 0.f) ? red[o] / dt + ob[o] : 0.f;
    }
}

extern "C" void kernel_launch(void* const* d_in, const int* in_sizes, int n_in,
                              void* d_out, int out_size, void* d_ws, size_t ws_size,
                              hipStream_t stream)
{
    const int* x        = (const int*)d_in[0];
    const int* ei       = (const int*)d_in[1];
    const int* ea       = (const int*)d_in[2];
    const int* batch    = (const int*)d_in[3];
    const float* node_emb = (const float*)d_in[4];
    const float* edge_emb = (const float*)d_in[5];
    const float* Wq    = (const float*)d_in[6];
    const float* Wk    = (const float*)d_in[7];
    const float* Wv    = (const float*)d_in[8];
    const float* We    = (const float*)d_in[9];
    const float* Wskip = (const float*)d_in[10];
    const float* bq    = (const float*)d_in[11];
    const float* bk    = (const float*)d_in[12];
    const float* bv    = (const float*)d_in[13];
    const float* bskip = (const float*)d_in[14];
    const float* gate_W = (const float*)d_in[15];
    const float* gate_b = (const float*)d_in[16];
    const float* out_W  = (const float*)d_in[17];
    const float* out_b  = (const float*)d_in[18];
    float* out = (float*)d_out;

    const size_t NH = (size_t)N_NODES * H;       // 3,200,000
    float* ws   = (float*)d_ws;
    float* hf32 = ws;                            // fp32 h (final layer only), NH floats
    unsigned* qs32 = (unsigned*)(ws + NH);       // q|s packed bf16, 64 dwords/node
    unsigned* kv32 = (unsigned*)(ws + 2 * NH);   // v|k packed bf16, 64 dwords/node
    ushort_t* wb16 = (ushort_t*)(ws + 3 * NH);   // 3*16384 bf16 weights (chunk-major), 24576 dwords
    ushort_t* hb16 = (ushort_t*)(ws + 3 * NH + 24576);  // bf16 h, NH ushorts = NH/2 dwords
    float* te   = ws + 3 * NH + 24576 + NH / 2;
    float* gate = te + LAYERS * 10 * H;
    int* row_start = (int*)(gate + N_NODES);
    int* row_end   = row_start + N_NODES;
    int* packed    = row_end + N_NODES;          // final CSR edge packets
    int* pmid      = packed + N_EDGES;           // bucket-sorted intermediate
    int* hist      = pmid + N_EDGES;             // NBUCK * NB_HISTB (transposed: [bucket][block])
    int* bstart    = hist + NBUCK * NB_HISTB;    // NBUCK + 1
    int* gs        = bstart + NBUCK + 1;         // 257 ints

    k_front<<<NB_FRONT, 256, 0, stream>>>(x, node_emb, hb16, edge_emb, We, te, ei, hist, batch, gs,
                                          Wq, Wk, Wv, Wskip, wb16);

    // layer 0: bucket scatter (blocks 0..127, cursor scan folded in) + MFMA gemm
    k_gemm_scatter<<<NB_HISTB + NB_GEMM, 256, 0, stream>>>(
        hb16, wb16, bq, bk, bv, bskip, qs32, kv32, ei, ea, hist, bstart, pmid);
    k_final<<<NBUCK, 256, 0, stream>>>(pmid, bstart, packed, row_start, row_end);
    k_agg<<<(N_NODES + 15) / 16, 256, 0, stream>>>(
        row_start, row_end, packed, qs32, kv32, te, nullptr, hb16, nullptr, nullptr, nullptr);

    for (int l = 1; l < LAYERS; l++) {
        k_gemm<<<NB_GEMM, 256, 0, stream>>>(
            hb16, wb16 + (size_t)l * 16384,
            bq + (size_t)l * H, bk + (size_t)l * H, bv + (size_t)l * H, bskip + (size_t)l * H,
            qs32, kv32);
        bool last = (l == LAYERS - 1);
        k_agg<<<(N_NODES + 15) / 16, 256, 0, stream>>>(
            row_start, row_end, packed, qs32, kv32, te + (size_t)l * 10 * H,
            last ? hf32 : nullptr, last ? nullptr : hb16,
            last ? gate_W : nullptr, last ? gate_b : nullptr, last ? gate : nullptr);
    }

    k_readout2<<<NGRAPH, 256, 0, stream>>>(hf32, out_W, out_b, gate, gs, out);
}

// Round 3
// 300.735 us; speedup vs baseline: 1.2593x; 1.0841x over previous
//
#include <hip/hip_runtime.h>
#include <hip/hip_bf16.h>

#define N_NODES 50000
#define N_EDGES 800000
#define H 64
#define ED 32
#define LAYERS 3
#define NGRAPH 256
#define OUTD 32
#define SCALE 0.125f

// bucketed counting sort for CSR build (no global atomics anywhere)
#define BNODES 128                                  // nodes per bucket (dst >> 7)
#define NBUCK ((N_NODES + BNODES - 1) / BNODES)     // 391
#define CURP_STRIDE 392
#define NB_HISTB 256                                // histogram / scatter blocks
#define EPB (N_EDGES / NB_HISTB)                    // 3125 edges per block

// fused front-end block ranges (hist first so CSR chain starts earliest)
#define NB_INIT 1563                                // 50000*8 bf16x8 writes / 256
#define NB_TE   8
#define NB_GB   2
#define NB_WB   192                                 // 3*16384 bf16 weight fragments / 256
#define NB_FRONT (NB_HISTB + NB_INIT + NB_TE + NB_GB + NB_WB)
#define NB_GEMM ((N_NODES + 63) / 64)               // 782

typedef __attribute__((ext_vector_type(8))) short bf16x8;
typedef __attribute__((ext_vector_type(4))) float f32x4;
typedef unsigned short ushort_t;

// fp32 -> bf16 round-to-nearest-even
__device__ __forceinline__ unsigned f2bf(float f) {
    unsigned u = __float_as_uint(f);
    return (u + 0x7FFFu + ((u >> 16) & 1u)) >> 16;
}

// 16-lane all-reduce sum via DPP (VALU only, no LDS pipe).
__device__ __forceinline__ float radd16(float x) {
    x += __int_as_float(__builtin_amdgcn_update_dpp(0, __float_as_int(x), 0xB1, 0xF, 0xF, true));   // quad_perm 1,0,3,2
    x += __int_as_float(__builtin_amdgcn_update_dpp(0, __float_as_int(x), 0x4E, 0xF, 0xF, true));   // quad_perm 2,3,0,1
    x += __int_as_float(__builtin_amdgcn_update_dpp(0, __float_as_int(x), 0x124, 0xF, 0xF, true));  // row_ror:4
    x += __int_as_float(__builtin_amdgcn_update_dpp(0, __float_as_int(x), 0x128, 0xF, 0xF, true));  // row_ror:8
    return x;
}

// ---------------- fused front end: bucket-hist | init_hb16 | te | gbounds | weights ----
__global__ __launch_bounds__(256) void k_front(
    const int* __restrict__ x, const float* __restrict__ node_emb, ushort_t* __restrict__ hb16,
    const float* __restrict__ edge_emb, const float* __restrict__ We, float* __restrict__ te,
    const int* __restrict__ ei, int* __restrict__ hist,
    const int* __restrict__ batch, int* __restrict__ gs,
    const float* __restrict__ Wq, const float* __restrict__ Wk,
    const float* __restrict__ Wv, const float* __restrict__ Wsk,
    ushort_t* __restrict__ wb16)
{
    __shared__ int lh[NBUCK];
    int b = blockIdx.x, t = threadIdx.x;
    if (b < NB_HISTB) {
        // per-block bucket histogram in LDS; transposed writeback hist[bucket][block]
        for (int i = t; i < NBUCK; i += 256) lh[i] = 0;
        __syncthreads();
        const int* dstp = ei + N_EDGES + b * EPB;
        for (int i = t; i < EPB; i += 256)
            atomicAdd(&lh[dstp[i] >> 7], 1);
        __syncthreads();
        for (int i = t; i < NBUCK; i += 256) hist[i * NB_HISTB + b] = lh[i];
    } else if (b < NB_HISTB + NB_INIT) {
        int i = (b - NB_HISTB) * 256 + t;
        if (i < N_NODES * 8) {
            int n = i >> 3, c8 = i & 7;
            const float* er = node_emb + (size_t)x[n] * H + c8 * 8;
            float4 f0 = *(const float4*)er;
            float4 f1 = *(const float4*)(er + 4);
            uint4 o;
            o.x = f2bf(f0.x) | (f2bf(f0.y) << 16);
            o.y = f2bf(f0.z) | (f2bf(f0.w) << 16);
            o.z = f2bf(f1.x) | (f2bf(f1.y) << 16);
            o.w = f2bf(f1.z) | (f2bf(f1.w) << 16);
            *(uint4*)(hb16 + (size_t)n * H + c8 * 8) = o;
        }
    } else if (b < NB_HISTB + NB_INIT + NB_TE) {
        int i = (b - NB_HISTB - NB_INIT) * 256 + t;
        if (i < LAYERS * 10 * H) {
            int c = i & 63;
            int cat = (i >> 6) % 10;
            int l = i / (10 * H);
            float acc = 0.f;
            for (int d = 0; d < ED; d++)
                acc += edge_emb[cat * ED + d] * We[((size_t)l * ED + d) * H + c];
            te[i] = acc;
        }
    } else if (b < NB_HISTB + NB_INIT + NB_TE + NB_GB) {
        int g = (b - NB_HISTB - NB_INIT - NB_TE) * 256 + t;
        if (g <= NGRAPH) {
            int lo = 0, hi = N_NODES;
            while (lo < hi) {
                int mid = (lo + hi) >> 1;
                if (batch[mid] < g) lo = mid + 1; else hi = mid;
            }
            gs[g] = lo;
        }
    } else {
        // chunk-major weight layout for conflict-free ds_read_b128:
        // wb16[l][c_id][r][j]  (c_id = kb*4+quad, r = ct*16+n16, j in [0,8))
        int g = (b - NB_HISTB - NB_INIT - NB_TE - NB_GB) * 256 + t;   // < 49152
        int l = g >> 14;
        int rem = g & 16383;
        int c_id = rem >> 11;
        int rr = (rem >> 3) & 255;
        int j = rem & 7;
        int mat = rr >> 6, n = rr & 63;
        int k = ((c_id >> 2) << 5) + ((c_id & 3) << 3) + j;
        const float* Wm = (mat == 0) ? Wq : (mat == 1) ? Wk : (mat == 2) ? Wv : Wsk;
        wb16[g] = (ushort_t)f2bf(Wm[(size_t)l * 4096 + k * 64 + n]);
    }
}

// ---------------- MFMA gemm body: wave = 16 nodes x 256 outputs ----------------
__device__ __forceinline__ void gemm_mfma_body(
    int bid, const ushort_t* __restrict__ hb, const ushort_t* __restrict__ wb,
    ushort_t* wlds,
    const float* __restrict__ bq, const float* __restrict__ bk,
    const float* __restrict__ bv, const float* __restrict__ bsk,
    unsigned* __restrict__ qs32, unsigned* __restrict__ kv32)
{
    int tid = threadIdx.x;
    {   // stage the layer's 32 KB weight block: 2048 uint4 / 256 threads = 8 each
        const uint4* s4 = (const uint4*)wb;
        uint4* d4 = (uint4*)wlds;
        #pragma unroll
        for (int it = 0; it < 8; it++) d4[it * 256 + tid] = s4[it * 256 + tid];
    }
    __syncthreads();
    int w = tid >> 6, lane = tid & 63;
    int n16 = lane & 15, quad = lane >> 4;
    int base = bid * 64;
    int nodeA = min(base + w * 16 + n16, N_NODES - 1);
    const ushort_t* hrow = hb + (size_t)nodeA * H;
    f32x4 acc[16];
    #pragma unroll
    for (int i = 0; i < 16; i++) acc[i] = (f32x4){0.f, 0.f, 0.f, 0.f};
    #pragma unroll
    for (int kb = 0; kb < 2; kb++) {
        bf16x8 afr = *(const bf16x8*)(hrow + kb * 32 + quad * 8);
        #pragma unroll
        for (int ct = 0; ct < 16; ct++) {
            const bf16x8* bp = (const bf16x8*)(wlds + (((kb * 4 + quad) << 11) + ((ct * 16 + n16) << 3)));
            acc[ct] = __builtin_amdgcn_mfma_f32_16x16x32_bf16(afr, *bp, acc[ct], 0, 0, 0);
        }
    }
    #pragma unroll
    for (int cc = 0; cc < 4; cc++) {
        int col = cc * 16 + n16;
        float bQ = bq[col], bK = bk[col], bV = bv[col], bS = bsk[col];
        #pragma unroll
        for (int r = 0; r < 4; r++) {
            int node = base + w * 16 + quad * 4 + r;
            if (node < N_NODES) {
                float qv = acc[cc][r] + bQ;
                float kk = acc[4 + cc][r] + bK;
                float vv = acc[8 + cc][r] + bV;
                float sv = acc[12 + cc][r] + bS;
                qs32[(size_t)node * 64 + col] = f2bf(qv) | (f2bf(sv) << 16);
                kv32[(size_t)node * 64 + col] = f2bf(vv) | (f2bf(kk) << 16);
            }
        }
    }
}

// layers 1,2: plain gemm
__global__ __launch_bounds__(256, 1) void k_gemm(
    const ushort_t* __restrict__ hb, const ushort_t* __restrict__ wb,
    const float* __restrict__ bq, const float* __restrict__ bk,
    const float* __restrict__ bv, const float* __restrict__ bsk,
    unsigned* __restrict__ qs32, unsigned* __restrict__ kv32)
{
    __shared__ __align__(16) char smem[32768];
    gemm_mfma_body(blockIdx.x, hb, wb, (ushort_t*)smem, bq, bk, bv, bsk, qs32, kv32);
}

// layer 0: gemm blocks [0, NB_GEMM) + ONE scan block (bid NB_GEMM) doing the
// cursor prefix once: curp[i][u] = #edges of bucket u in hist-blocks < i; bstart scan.
__global__ __launch_bounds__(256, 1) void k_gemm_scan(
    const ushort_t* __restrict__ hb, const ushort_t* __restrict__ wb,
    const float* __restrict__ bq, const float* __restrict__ bk,
    const float* __restrict__ bv, const float* __restrict__ bsk,
    unsigned* __restrict__ qs32, unsigned* __restrict__ kv32,
    const int* __restrict__ hist, int* __restrict__ curp, int* __restrict__ bstart)
{
    __shared__ __align__(16) char smem[32768];
    int b = blockIdx.x, t = threadIdx.x;
    if (b < NB_GEMM) {
        gemm_mfma_body(b, hb, wb, (ushort_t*)smem, bq, bk, bv, bsk, qs32, kv32);
    } else {
        int* totS = (int*)smem;           // NBUCK
        int* part = totS + CURP_STRIDE;   // 256
        #pragma unroll
        for (int rep = 0; rep < 2; rep++) {
            int u = t + rep * 256;
            if (u < NBUCK) {
                int run = 0;
                const uint4* hp = (const uint4*)(hist + u * NB_HISTB);
                int* cp = curp + u;
                for (int c = 0; c < NB_HISTB / 4; c++) {
                    uint4 v = hp[c];
                    cp[(c * 4 + 0) * CURP_STRIDE] = run; run += (int)v.x;
                    cp[(c * 4 + 1) * CURP_STRIDE] = run; run += (int)v.y;
                    cp[(c * 4 + 2) * CURP_STRIDE] = run; run += (int)v.z;
                    cp[(c * 4 + 3) * CURP_STRIDE] = run; run += (int)v.w;
                }
                totS[u] = run;
            }
        }
        __syncthreads();
        int u0 = t * 2, u1 = t * 2 + 1;
        int a0 = (u0 < NBUCK) ? totS[u0] : 0;
        int a1 = (u1 < NBUCK) ? totS[u1] : 0;
        part[t] = a0 + a1;
        __syncthreads();
        for (int off = 1; off < 256; off <<= 1) {
            int add = (t >= off) ? part[t - off] : 0;
            __syncthreads();
            part[t] += add;
            __syncthreads();
        }
        int excl = part[t] - (a0 + a1);
        if (u0 < NBUCK) bstart[u0] = excl;
        if (u1 < NBUCK) bstart[u1] = excl + a0;
        if (t == 0) bstart[NBUCK] = N_EDGES;
    }
}

// ---------------- scatter: rank via LDS atomics against precomputed cursors -----------
__global__ __launch_bounds__(256) void k_scatter(
    const int* __restrict__ ei, const int* __restrict__ ea,
    const int* __restrict__ bstart, const int* __restrict__ curp,
    int* __restrict__ pmid)
{
    __shared__ int curS[NBUCK];
    int b = blockIdx.x, t = threadIdx.x;
    for (int u = t; u < NBUCK; u += 256)
        curS[u] = bstart[u] + curp[b * CURP_STRIDE + u];
    __syncthreads();
    int e0 = b * EPB;
    for (int i = t; i < EPB; i += 256) {
        int e = e0 + i;
        int src = ei[e], dst = ei[N_EDGES + e], cat = ea[e];
        int pos = atomicAdd(&curS[dst >> 7], 1);
        pmid[pos] = src | (cat << 16) | ((dst & 127) << 20);
    }
}

// ---------------- per-bucket finalize: exact CSR rows + in-bucket ordering -------------
__global__ __launch_bounds__(256) void k_final(
    const int* __restrict__ pmid, const int* __restrict__ bstart,
    int* __restrict__ packed, int* __restrict__ row_start, int* __restrict__ row_end)
{
    __shared__ int cnt[BNODES];
    __shared__ int scan_s[BNODES];
    int b = blockIdx.x, t = threadIdx.x;
    int beg = bstart[b], end = bstart[b + 1];
    if (t < BNODES) cnt[t] = 0;
    __syncthreads();
    for (int e = beg + t; e < end; e += 256)
        atomicAdd(&cnt[(pmid[e] >> 20) & 127], 1);
    __syncthreads();
    if (t < BNODES) scan_s[t] = cnt[t];
    __syncthreads();
    for (int off = 1; off < BNODES; off <<= 1) {
        int add = (t >= off && t < BNODES) ? scan_s[t - off] : 0;
        __syncthreads();
        if (t < BNODES) scan_s[t] += add;
        __syncthreads();
    }
    if (t < BNODES) {
        int c = cnt[t];
        int excl = scan_s[t] - c;          // exclusive within bucket
        int node = b * BNODES + t;
        if (node < N_NODES) {
            row_start[node] = beg + excl;
            row_end[node] = beg + excl + c;
        }
        cnt[t] = beg + excl;               // reuse as cursor
    }
    __syncthreads();
    for (int e = beg + t; e < end; e += 256) {
        int p = pmid[e];
        int pos = atomicAdd(&cnt[(p >> 20) & 127], 1);
        packed[pos] = p & 0xFFFFF;         // src | cat<<16
    }
}

// per-edge load bundle
struct EdgeLd { uint4 kv; float4 t; };
__device__ __forceinline__ EdgeLd edge_load(int pkt, const unsigned* __restrict__ kv32,
                                            const float* tel, int i16) {
    EdgeLd r;
    r.kv = *(const uint4*)(kv32 + ((size_t)(pkt & 0xFFFF) << 6) + (i16 << 2));
    r.t  = *(const float4*)(tel + ((pkt >> 16) << 6) + (i16 << 2));
    return r;
}
__device__ __forceinline__ float edge_dot(const EdgeLd& e, const float4& q4) {
    float p;
    p = (__uint_as_float(e.kv.x & 0xFFFF0000u) + e.t.x) * q4.x;
    p = fmaf(__uint_as_float(e.kv.y & 0xFFFF0000u) + e.t.y, q4.y, p);
    p = fmaf(__uint_as_float(e.kv.z & 0xFFFF0000u) + e.t.z, q4.z, p);
    p = fmaf(__uint_as_float(e.kv.w & 0xFFFF0000u) + e.t.w, q4.w, p);
    return radd16(p) * SCALE;
}
__device__ __forceinline__ float4 edge_val(const EdgeLd& e) {
    float4 v;
    v.x = __uint_as_float(e.kv.x << 16) + e.t.x;
    v.y = __uint_as_float(e.kv.y << 16) + e.t.y;
    v.z = __uint_as_float(e.kv.z << 16) + e.t.z;
    v.w = __uint_as_float(e.kv.w << 16) + e.t.w;
    return v;
}

// ---------------- fused gather: one dst per 16-lane group (4 dsts/wave) -------------
__global__ __launch_bounds__(256) void k_agg(
    const int* __restrict__ row_start, const int* __restrict__ row_end,
    const int* __restrict__ packed,
    const unsigned* __restrict__ qs32, const unsigned* __restrict__ kv32,
    const float* __restrict__ te, float* __restrict__ hf, ushort_t* __restrict__ hbo,
    const float* __restrict__ gW, const float* __restrict__ gb, float* __restrict__ gate)
{
    __shared__ float tel[10 * 64];
    int t = threadIdx.x;
    int wave = t >> 6, lane = t & 63;
    int g = lane >> 4, i16 = lane & 15;
    int dst = blockIdx.x * 16 + wave * 4 + g;
    bool active = dst < N_NODES;
    int beg = 0, end = 0;
    uint4 uq = {0u, 0u, 0u, 0u};
    if (active) {
        beg = row_start[dst];
        end = row_end[dst];
        uq = *(const uint4*)(qs32 + (size_t)dst * 64 + (i16 << 2));   // q lo16 | s hi16, x4 channels
    }
    for (int i = t; i < 10 * 64; i += 256) tel[i] = te[i];
    __syncthreads();
    float4 q4, s4;
    q4.x = __uint_as_float(uq.x << 16); s4.x = __uint_as_float(uq.x & 0xFFFF0000u);
    q4.y = __uint_as_float(uq.y << 16); s4.y = __uint_as_float(uq.y & 0xFFFF0000u);
    q4.z = __uint_as_float(uq.z << 16); s4.z = __uint_as_float(uq.z & 0xFFFF0000u);
    q4.w = __uint_as_float(uq.w << 16); s4.w = __uint_as_float(uq.w & 0xFFFF0000u);
    float m = -1e30f, l = 0.f;
    float4 acc = {0.f, 0.f, 0.f, 0.f};
    int e = beg;
    for (; e + 3 < end; e += 4) {
        int p0 = packed[e], p1 = packed[e + 1], p2 = packed[e + 2], p3 = packed[e + 3];
        EdgeLd e0 = edge_load(p0, kv32, tel, i16);
        EdgeLd e1 = edge_load(p1, kv32, tel, i16);
        EdgeLd e2 = edge_load(p2, kv32, tel, i16);
        EdgeLd e3 = edge_load(p3, kv32, tel, i16);
        float a0 = edge_dot(e0, q4), a1 = edge_dot(e1, q4);
        float a2 = edge_dot(e2, q4), a3 = edge_dot(e3, q4);
        float mn = fmaxf(m, fmaxf(fmaxf(a0, a1), fmaxf(a2, a3)));
        float corr = __expf(m - mn);
        float w0 = __expf(a0 - mn), w1 = __expf(a1 - mn);
        float w2 = __expf(a2 - mn), w3 = __expf(a3 - mn);
        float4 v0 = edge_val(e0), v1 = edge_val(e1), v2 = edge_val(e2), v3 = edge_val(e3);
        acc.x = fmaf(w0, v0.x, fmaf(w1, v1.x, fmaf(w2, v2.x, fmaf(w3, v3.x, acc.x * corr))));
        acc.y = fmaf(w0, v0.y, fmaf(w1, v1.y, fmaf(w2, v2.y, fmaf(w3, v3.y, acc.y * corr))));
        acc.z = fmaf(w0, v0.z, fmaf(w1, v1.z, fmaf(w2, v2.z, fmaf(w3, v3.z, acc.z * corr))));
        acc.w = fmaf(w0, v0.w, fmaf(w1, v1.w, fmaf(w2, v2.w, fmaf(w3, v3.w, acc.w * corr))));
        l = fmaf(l, corr, (w0 + w1) + (w2 + w3));
        m = mn;
    }
    for (; e < end; e++) {
        int pkt = packed[e];
        EdgeLd e0 = edge_load(pkt, kv32, tel, i16);
        float a = edge_dot(e0, q4);
        float mn = fmaxf(m, a);
        float corr = __expf(m - mn);
        float w = __expf(a - mn);
        float4 v4 = edge_val(e0);
        acc.x = fmaf(w, v4.x, acc.x * corr);
        acc.y = fmaf(w, v4.y, acc.y * corr);
        acc.z = fmaf(w, v4.z, acc.z * corr);
        acc.w = fmaf(w, v4.w, acc.w * corr);
        l = fmaf(l, corr, w);
        m = mn;
    }
    float inv = (l > 0.f) ? 1.f / l : 0.f;
    float4 hv;
    hv.x = fmaxf(acc.x * inv + s4.x, 0.f);
    hv.y = fmaxf(acc.y * inv + s4.y, 0.f);
    hv.z = fmaxf(acc.z * inv + s4.z, 0.f);
    hv.w = fmaxf(acc.w * inv + s4.w, 0.f);
    if (active) {
        if (hbo) {
            uint2 o;
            o.x = f2bf(hv.x) | (f2bf(hv.y) << 16);
            o.y = f2bf(hv.z) | (f2bf(hv.w) << 16);
            *(uint2*)(hbo + (size_t)dst * H + (i16 << 2)) = o;
        } else {
            *(float4*)(hf + (size_t)dst * H + (i16 << 2)) = hv;
        }
    }
    if (gW && active) {
        float4 g4 = *(const float4*)(gW + (i16 << 2));
        float p = hv.x * g4.x + hv.y * g4.y + hv.z * g4.z + hv.w * g4.w;
        p = radd16(p);
        if (i16 == 0) gate[dst] = p + gb[0];
    }
}

// ---------------- fused per-graph readout (W column in registers) ----------------
__global__ __launch_bounds__(256) void k_readout2(
    const float* __restrict__ h, const float* __restrict__ oW,
    const float* __restrict__ ob, const float* __restrict__ gate,
    const int* __restrict__ gs, float* __restrict__ out)
{
    __shared__ float hs[8][H + 1];
    __shared__ float red[256];
    __shared__ float den_s[8];
    __shared__ float gmax_s, den_tot;
    int t = threadIdx.x;
    int g = blockIdx.x;
    int ln = t >> 5, o = t & 31;
    float wreg[H];
    #pragma unroll
    for (int i = 0; i < H; i++) wreg[i] = oW[i * OUTD + o];
    int beg = gs[g], end = gs[g + 1];
    float mx = -INFINITY;
    for (int n = beg + t; n < end; n += 256) mx = fmaxf(mx, gate[n]);
    red[t] = mx;
    __syncthreads();
    for (int sft = 128; sft > 0; sft >>= 1) {
        if (t < sft) red[t] = fmaxf(red[t], red[t + sft]);
        __syncthreads();
    }
    if (t == 0) gmax_s = red[0];
    __syncthreads();
    float gm = gmax_s;
    float acc = 0.f, den = 0.f;
    for (int n0 = beg; n0 < end; n0 += 8) {
        __syncthreads();
        for (int i = t; i < 8 * H; i += 256) {
            int r = i >> 6, c = i & 63;
            int n = n0 + r;
            hs[r][c] = (n < end) ? h[(size_t)n * H + c] : 0.f;
        }
        __syncthreads();
        int n = n0 + ln;
        if (n < end) {
            float wt = __expf(gate[n] - gm);
            float d0 = 0.f;
            #pragma unroll
            for (int i = 0; i < H; i++) d0 += hs[ln][i] * wreg[i];
            acc += wt * d0;
            if (o == 0) den += wt;
        }
    }
    __syncthreads();
    red[t] = acc;
    if (o == 0) den_s[ln] = den;
    __syncthreads();
    for (int sft = 4; sft >= 1; sft >>= 1) {
        if (ln < sft) red[t] += red[t + sft * 32];
        __syncthreads();
    }
    if (t == 0) {
        float dt = 0.f;
        #pragma unroll
        for (int i = 0; i < 8; i++) dt += den_s[i];
        den_tot = dt;
    }
    __syncthreads();
    if (ln == 0) {
        float dt = den_tot;
        out[g * OUTD + o] = (dt > 0.f) ? red[o] / dt + ob[o] : 0.f;
    }
}

extern "C" void kernel_launch(void* const* d_in, const int* in_sizes, int n_in,
                              void* d_out, int out_size, void* d_ws, size_t ws_size,
                              hipStream_t stream)
{
    const int* x        = (const int*)d_in[0];
    const int* ei       = (const int*)d_in[1];
    const int* ea       = (const int*)d_in[2];
    const int* batch    = (const int*)d_in[3];
    const float* node_emb = (const float*)d_in[4];
    const float* edge_emb = (const float*)d_in[5];
    const float* Wq    = (const float*)d_in[6];
    const float* Wk    = (const float*)d_in[7];
    const float* Wv    = (const float*)d_in[8];
    const float* We    = (const float*)d_in[9];
    const float* Wskip = (const float*)d_in[10];
    const float* bq    = (const float*)d_in[11];
    const float* bk    = (const float*)d_in[12];
    const float* bv    = (const float*)d_in[13];
    const float* bskip = (const float*)d_in[14];
    const float* gate_W = (const float*)d_in[15];
    const float* gate_b = (const float*)d_in[16];
    const float* out_W  = (const float*)d_in[17];
    const float* out_b  = (const float*)d_in[18];
    float* out = (float*)d_out;

    const size_t NH = (size_t)N_NODES * H;       // 3,200,000
    float* ws   = (float*)d_ws;
    float* hf32 = ws;                            // fp32 h (final layer only), NH floats
    unsigned* qs32 = (unsigned*)(ws + NH);       // q|s packed bf16, 64 dwords/node
    unsigned* kv32 = (unsigned*)(ws + 2 * NH);   // v|k packed bf16, 64 dwords/node
    ushort_t* wb16 = (ushort_t*)(ws + 3 * NH);   // 3*16384 bf16 weights (chunk-major)
    ushort_t* hb16 = (ushort_t*)(ws + 3 * NH + 24576);  // bf16 h
    float* te   = ws + 3 * NH + 24576 + NH / 2;
    float* gate = te + LAYERS * 10 * H;
    int* row_start = (int*)(gate + N_NODES);
    int* row_end   = row_start + N_NODES;
    int* packed    = row_end + N_NODES;          // final CSR edge packets
    int* pmid      = packed + N_EDGES;           // bucket-sorted intermediate
    int* hist      = pmid + N_EDGES;             // NBUCK * NB_HISTB (transposed: [bucket][block])
    int* curp      = hist + NBUCK * NB_HISTB;    // NB_HISTB * CURP_STRIDE block-prefixes
    int* bstart    = curp + NB_HISTB * CURP_STRIDE;  // NBUCK + 1
    int* gs        = bstart + NBUCK + 1;         // 257 ints

    k_front<<<NB_FRONT, 256, 0, stream>>>(x, node_emb, hb16, edge_emb, We, te, ei, hist, batch, gs,
                                          Wq, Wk, Wv, Wskip, wb16);

    // layer 0 gemm + single hidden scan block
    k_gemm_scan<<<NB_GEMM + 1, 256, 0, stream>>>(
        hb16, wb16, bq, bk, bv, bskip, qs32, kv32, hist, curp, bstart);
    k_scatter<<<NB_HISTB, 256, 0, stream>>>(ei, ea, bstart, curp, pmid);
    k_final<<<NBUCK, 256, 0, stream>>>(pmid, bstart, packed, row_start, row_end);
    k_agg<<<(N_NODES + 15) / 16, 256, 0, stream>>>(
        row_start, row_end, packed, qs32, kv32, te, nullptr, hb16, nullptr, nullptr, nullptr);

    for (int l = 1; l < LAYERS; l++) {
        k_gemm<<<NB_GEMM, 256, 0, stream>>>(
            hb16, wb16 + (size_t)l * 16384,
            bq + (size_t)l * H, bk + (size_t)l * H, bv + (size_t)l * H, bskip + (size_t)l * H,
            qs32, kv32);
        bool last = (l == LAYERS - 1);
        k_agg<<<(N_NODES + 15) / 16, 256, 0, stream>>>(
            row_start, row_end, packed, qs32, kv32, te + (size_t)l * 10 * H,
            last ? hf32 : nullptr, last ? nullptr : hb16,
            last ? gate_W : nullptr, last ? gate_b : nullptr, last ? gate : nullptr);
    }

    k_readout2<<<NGRAPH, 256, 0, stream>>>(hf32, out_W, out_b, gate, gs, out);
}

// Round 4
// 269.905 us; speedup vs baseline: 1.4031x; 1.1142x over previous
//
#include <hip/hip_runtime.h>
#include <hip/hip_bf16.h>

#define N_NODES 50000
#define N_EDGES 800000
#define H 64
#define ED 32
#define LAYERS 3
#define NGRAPH 256
#define OUTD 32
#define SCALE 0.125f

// bucketed counting sort for CSR build (no global atomics anywhere)
#define BNODES 128                                  // nodes per bucket (dst >> 7)
#define NBUCK 391                                   // ceil(50000/128)
#define NB_HISTB 256                                // histogram / scatter blocks
#define EPB (N_EDGES / NB_HISTB)                    // 3125 edges per block

// fused front-end virtual block ranges
#define FB_HIST 256
#define FB_TE   8
#define FB_GB   2
#define FB_WB   192                                 // 3*16384 bf16 weight fragments / 256
#define FB_TAB  42                                  // layer-0 qkv table, 1 block per category
#define NB_FRONT (FB_HIST + FB_TE + FB_GB + FB_WB + FB_TAB)

#define NB_GATHER 3125                              // 800K uint4 gather positions / 256
#define NB_SCAN   98                                // 391 buckets / 4 per block
#define NB_AGG    3125                              // 50000 dsts / 16

typedef __attribute__((ext_vector_type(8))) short bf16x8;
typedef __attribute__((ext_vector_type(4))) float f32x4;
typedef unsigned short ushort_t;

// fp32 -> bf16 round-to-nearest-even
__device__ __forceinline__ unsigned f2bf(float f) {
    unsigned u = __float_as_uint(f);
    return (u + 0x7FFFu + ((u >> 16) & 1u)) >> 16;
}

// 16-lane all-reduce sum via DPP (VALU only, no LDS pipe).
__device__ __forceinline__ float radd16(float x) {
    x += __int_as_float(__builtin_amdgcn_update_dpp(0, __float_as_int(x), 0xB1, 0xF, 0xF, true));   // quad_perm 1,0,3,2
    x += __int_as_float(__builtin_amdgcn_update_dpp(0, __float_as_int(x), 0x4E, 0xF, 0xF, true));   // quad_perm 2,3,0,1
    x += __int_as_float(__builtin_amdgcn_update_dpp(0, __float_as_int(x), 0x124, 0xF, 0xF, true));  // row_ror:4
    x += __int_as_float(__builtin_amdgcn_update_dpp(0, __float_as_int(x), 0x128, 0xF, 0xF, true));  // row_ror:8
    return x;
}

// shared prologue: exclusive scan of 391 bucket totals -> bst[] in LDS
__device__ __forceinline__ void build_bstart(const int* __restrict__ tot,
                                             int* bst, int* part, int t) {
    int u0 = t * 2, u1 = t * 2 + 1;
    int a0 = (u0 < NBUCK) ? tot[u0] : 0;
    int a1 = (u1 < NBUCK) ? tot[u1] : 0;
    part[t] = a0 + a1;
    __syncthreads();
    for (int off = 1; off < 256; off <<= 1) {
        int add = (t >= off) ? part[t - off] : 0;
        __syncthreads();
        part[t] += add;
        __syncthreads();
    }
    int excl = part[t] - (a0 + a1);
    if (u0 < NBUCK) bst[u0] = excl;
    if (u1 < NBUCK) bst[u1] = excl + a0;
    if (t == 0) bst[NBUCK] = N_EDGES;
    __syncthreads();
}

// ---------------- fused front end: hist | te | gbounds | weights | layer0-table --------
__global__ __launch_bounds__(256) void k_front(
    const int* __restrict__ x, const float* __restrict__ node_emb,
    const float* __restrict__ edge_emb, const float* __restrict__ We, float* __restrict__ te,
    const int* __restrict__ ei, int* __restrict__ hist,
    const int* __restrict__ batch, int* __restrict__ gs,
    const float* __restrict__ Wq, const float* __restrict__ Wk,
    const float* __restrict__ Wv, const float* __restrict__ Wsk,
    const float* __restrict__ bq, const float* __restrict__ bk,
    const float* __restrict__ bv, const float* __restrict__ bsk,
    ushort_t* __restrict__ wb16,
    unsigned* __restrict__ tqs, unsigned* __restrict__ tkv)
{
    __shared__ int lh[NBUCK];
    __shared__ float tb[4][64];
    int b = blockIdx.x, t = threadIdx.x;
    if (b < FB_HIST) {
        // per-block bucket histogram in LDS; transposed writeback hist[bucket][block]
        for (int i = t; i < NBUCK; i += 256) lh[i] = 0;
        __syncthreads();
        const int* dstp = ei + N_EDGES + b * EPB;
        for (int i = t; i < EPB; i += 256)
            atomicAdd(&lh[dstp[i] >> 7], 1);
        __syncthreads();
        for (int i = t; i < NBUCK; i += 256) hist[i * NB_HISTB + b] = lh[i];
    } else if (b < FB_HIST + FB_TE) {
        int i = (b - FB_HIST) * 256 + t;
        if (i < LAYERS * 10 * H) {
            int c = i & 63;
            int cat = (i >> 6) % 10;
            int l = i / (10 * H);
            float acc = 0.f;
            for (int d = 0; d < ED; d++)
                acc += edge_emb[cat * ED + d] * We[((size_t)l * ED + d) * H + c];
            te[i] = acc;
        }
    } else if (b < FB_HIST + FB_TE + FB_GB) {
        int g = (b - FB_HIST - FB_TE) * 256 + t;
        if (g <= NGRAPH) {
            int lo = 0, hi = N_NODES;
            while (lo < hi) {
                int mid = (lo + hi) >> 1;
                if (batch[mid] < g) lo = mid + 1; else hi = mid;
            }
            gs[g] = lo;
        }
    } else if (b < FB_HIST + FB_TE + FB_GB + FB_WB) {
        // chunk-major weight layout for conflict-free ds_read_b128 / direct L2 frags:
        // wb16[l][c_id][r][j]  (c_id = kb*4+quad, r = ct*16+n16, j in [0,8))
        int g = (b - FB_HIST - FB_TE - FB_GB) * 256 + t;   // < 49152
        int l = g >> 14;
        int rem = g & 16383;
        int c_id = rem >> 11;
        int rr = (rem >> 3) & 255;
        int j = rem & 7;
        int mat = rr >> 6, n = rr & 63;
        int k = ((c_id >> 2) << 5) + ((c_id & 3) << 3) + j;
        const float* Wm = (mat == 0) ? Wq : (mat == 1) ? Wk : (mat == 2) ? Wv : Wsk;
        wb16[g] = (ushort_t)f2bf(Wm[(size_t)l * 4096 + k * 64 + n]);
    } else {
        // layer-0 qkv table: one block per node category, fp32 matvec (exact)
        int cat = b - (FB_HIST + FB_TE + FB_GB + FB_WB);
        int mat = t >> 6, c = t & 63;
        const float* Wm = (mat == 0) ? Wq : (mat == 1) ? Wk : (mat == 2) ? Wv : Wsk;
        const float* bm = (mat == 0) ? bq : (mat == 1) ? bk : (mat == 2) ? bv : bsk;
        float acc = bm[c];
        for (int k = 0; k < H; k++)
            acc += node_emb[cat * H + k] * Wm[k * 64 + c];
        tb[mat][c] = acc;
        __syncthreads();
        if (t < 64) {
            tqs[cat * 64 + t] = f2bf(tb[0][t]) | (f2bf(tb[3][t]) << 16);   // q | skip
            tkv[cat * 64 + t] = f2bf(tb[2][t]) | (f2bf(tb[1][t]) << 16);   // v | k
        }
    }
}

// ---------------- gather layer-0 qkv from table | per-bucket block-prefix scan --------
__global__ __launch_bounds__(256) void k_scan_gather(
    const int* __restrict__ x,
    const unsigned* __restrict__ tqs, const unsigned* __restrict__ tkv,
    unsigned* __restrict__ qs_out, unsigned* __restrict__ kv_out,
    int* __restrict__ hist, int* __restrict__ tot)
{
    __shared__ int sv[256];
    int b = blockIdx.x, t = threadIdx.x;
    if (b < NB_GATHER) {
        int idx = b * 256 + t;           // < 800000 uint4 positions
        int n = idx >> 4, c4 = idx & 15;
        int cat = x[n];
        ((uint4*)qs_out)[idx] = ((const uint4*)tqs)[cat * 16 + c4];
        ((uint4*)kv_out)[idx] = ((const uint4*)tkv)[cat * 16 + c4];
    } else {
        int sb = b - NB_GATHER;
        for (int r = 0; r < 4; r++) {
            int u = sb * 4 + r;
            if (u < NBUCK) {
                int v = hist[u * NB_HISTB + t];
                sv[t] = v;
                __syncthreads();
                for (int off = 1; off < 256; off <<= 1) {
                    int add = (t >= off) ? sv[t - off] : 0;
                    __syncthreads();
                    sv[t] += add;
                    __syncthreads();
                }
                int incl = sv[t];
                hist[u * NB_HISTB + t] = incl - v;   // exclusive prefix, in place
                if (t == 255) tot[u] = incl;
                __syncthreads();
            }
        }
    }
}

// ---------------- scatter: rank via LDS atomics against per-block cursors -------------
__global__ __launch_bounds__(256) void k_scatter(
    const int* __restrict__ ei, const int* __restrict__ ea,
    const int* __restrict__ hist, const int* __restrict__ tot,
    int* __restrict__ pmid)
{
    __shared__ int bst[NBUCK + 1];
    __shared__ int part[256];
    __shared__ int curS[NBUCK];
    int b = blockIdx.x, t = threadIdx.x;
    build_bstart(tot, bst, part, t);
    for (int u = t; u < NBUCK; u += 256)
        curS[u] = bst[u] + hist[u * NB_HISTB + b];
    __syncthreads();
    int e0 = b * EPB;
    for (int i = t; i < EPB; i += 256) {
        int e = e0 + i;
        int src = ei[e], dst = ei[N_EDGES + e], cat = ea[e];
        int pos = atomicAdd(&curS[dst >> 7], 1);
        pmid[pos] = src | (cat << 16) | ((dst & 127) << 20);
    }
}

// ---------------- per-bucket finalize: exact CSR rows + in-bucket ordering -------------
__global__ __launch_bounds__(256) void k_final(
    const int* __restrict__ pmid, const int* __restrict__ tot,
    int* __restrict__ packed, int* __restrict__ row_start, int* __restrict__ row_end)
{
    __shared__ int bst[NBUCK + 1];
    __shared__ int part[256];
    __shared__ int cnt[BNODES];
    __shared__ int scan_s[BNODES];
    int b = blockIdx.x, t = threadIdx.x;
    build_bstart(tot, bst, part, t);
    int beg = bst[b], end = bst[b + 1];
    if (t < BNODES) cnt[t] = 0;
    __syncthreads();
    for (int e = beg + t; e < end; e += 256)
        atomicAdd(&cnt[(pmid[e] >> 20) & 127], 1);
    __syncthreads();
    if (t < BNODES) scan_s[t] = cnt[t];
    __syncthreads();
    for (int off = 1; off < BNODES; off <<= 1) {
        int add = (t >= off && t < BNODES) ? scan_s[t - off] : 0;
        __syncthreads();
        if (t < BNODES) scan_s[t] += add;
        __syncthreads();
    }
    if (t < BNODES) {
        int c = cnt[t];
        int excl = scan_s[t] - c;          // exclusive within bucket
        int node = b * BNODES + t;
        if (node < N_NODES) {
            row_start[node] = beg + excl;
            row_end[node] = beg + excl + c;
        }
        cnt[t] = beg + excl;               // reuse as cursor
    }
    __syncthreads();
    for (int e = beg + t; e < end; e += 256) {
        int p = pmid[e];
        int pos = atomicAdd(&cnt[(p >> 20) & 127], 1);
        packed[pos] = p & 0xFFFFF;         // src | cat<<16
    }
}

// per-edge load bundle
struct EdgeLd { uint4 kv; float4 t; };
__device__ __forceinline__ EdgeLd edge_load(int pkt, const unsigned* __restrict__ kv32,
                                            const float* tel, int i16) {
    EdgeLd r;
    r.kv = *(const uint4*)(kv32 + ((size_t)(pkt & 0xFFFF) << 6) + (i16 << 2));
    r.t  = *(const float4*)(tel + ((pkt >> 16) << 6) + (i16 << 2));
    return r;
}
__device__ __forceinline__ float edge_dot(const EdgeLd& e, const float4& q4) {
    float p;
    p = (__uint_as_float(e.kv.x & 0xFFFF0000u) + e.t.x) * q4.x;
    p = fmaf(__uint_as_float(e.kv.y & 0xFFFF0000u) + e.t.y, q4.y, p);
    p = fmaf(__uint_as_float(e.kv.z & 0xFFFF0000u) + e.t.z, q4.z, p);
    p = fmaf(__uint_as_float(e.kv.w & 0xFFFF0000u) + e.t.w, q4.w, p);
    return radd16(p) * SCALE;
}
__device__ __forceinline__ float4 edge_val(const EdgeLd& e) {
    float4 v;
    v.x = __uint_as_float(e.kv.x << 16) + e.t.x;
    v.y = __uint_as_float(e.kv.y << 16) + e.t.y;
    v.z = __uint_as_float(e.kv.z << 16) + e.t.z;
    v.w = __uint_as_float(e.kv.w << 16) + e.t.w;
    return v;
}

// ---------------- fused gather-attention + next-layer qkv GEMM epilogue --------------
// one dst per 16-lane group (4 dsts/wave, 16 dsts/block; 3125*16 = 50000 exactly).
// layers 0,1: wbn != null -> epilogue computes next layer's q/k/v/skip via MFMA
// layer 2:    hf/gW != null -> write fp32 h + gate
__global__ __launch_bounds__(256, 4) void k_agg(
    const int* __restrict__ row_start, const int* __restrict__ row_end,
    const int* __restrict__ packed,
    const unsigned* __restrict__ qs_in, const unsigned* __restrict__ kv_in,
    const float* __restrict__ te,
    const ushort_t* __restrict__ wbn, const float* __restrict__ bqn,
    const float* __restrict__ bkn, const float* __restrict__ bvn,
    const float* __restrict__ bsn,
    unsigned* __restrict__ qs_out, unsigned* __restrict__ kv_out,
    float* __restrict__ hf, const float* __restrict__ gW,
    const float* __restrict__ gb, float* __restrict__ gate)
{
    __shared__ float tel[10 * 64];
    __shared__ ushort_t hs16[16 * 64];
    int t = threadIdx.x;
    int wave = t >> 6, lane = t & 63;
    int g = lane >> 4, i16 = lane & 15;
    int dst = blockIdx.x * 16 + wave * 4 + g;
    int beg = row_start[dst];
    int end = row_end[dst];
    uint4 uq = *(const uint4*)(qs_in + (size_t)dst * 64 + (i16 << 2));   // q lo16 | s hi16
    for (int i = t; i < 10 * 64; i += 256) tel[i] = te[i];
    __syncthreads();
    float4 q4, s4;
    q4.x = __uint_as_float(uq.x << 16); s4.x = __uint_as_float(uq.x & 0xFFFF0000u);
    q4.y = __uint_as_float(uq.y << 16); s4.y = __uint_as_float(uq.y & 0xFFFF0000u);
    q4.z = __uint_as_float(uq.z << 16); s4.z = __uint_as_float(uq.z & 0xFFFF0000u);
    q4.w = __uint_as_float(uq.w << 16); s4.w = __uint_as_float(uq.w & 0xFFFF0000u);
    float m = -1e30f, l = 0.f;
    float4 acc = {0.f, 0.f, 0.f, 0.f};
    int e = beg;
    for (; e + 3 < end; e += 4) {
        int p0 = packed[e], p1 = packed[e + 1], p2 = packed[e + 2], p3 = packed[e + 3];
        EdgeLd e0 = edge_load(p0, kv_in, tel, i16);
        EdgeLd e1 = edge_load(p1, kv_in, tel, i16);
        EdgeLd e2 = edge_load(p2, kv_in, tel, i16);
        EdgeLd e3 = edge_load(p3, kv_in, tel, i16);
        float a0 = edge_dot(e0, q4), a1 = edge_dot(e1, q4);
        float a2 = edge_dot(e2, q4), a3 = edge_dot(e3, q4);
        float mn = fmaxf(m, fmaxf(fmaxf(a0, a1), fmaxf(a2, a3)));
        float corr = __expf(m - mn);
        float w0 = __expf(a0 - mn), w1 = __expf(a1 - mn);
        float w2 = __expf(a2 - mn), w3 = __expf(a3 - mn);
        float4 v0 = edge_val(e0), v1 = edge_val(e1), v2 = edge_val(e2), v3 = edge_val(e3);
        acc.x = fmaf(w0, v0.x, fmaf(w1, v1.x, fmaf(w2, v2.x, fmaf(w3, v3.x, acc.x * corr))));
        acc.y = fmaf(w0, v0.y, fmaf(w1, v1.y, fmaf(w2, v2.y, fmaf(w3, v3.y, acc.y * corr))));
        acc.z = fmaf(w0, v0.z, fmaf(w1, v1.z, fmaf(w2, v2.z, fmaf(w3, v3.z, acc.z * corr))));
        acc.w = fmaf(w0, v0.w, fmaf(w1, v1.w, fmaf(w2, v2.w, fmaf(w3, v3.w, acc.w * corr))));
        l = fmaf(l, corr, (w0 + w1) + (w2 + w3));
        m = mn;
    }
    for (; e < end; e++) {
        int pkt = packed[e];
        EdgeLd e0 = edge_load(pkt, kv_in, tel, i16);
        float a = edge_dot(e0, q4);
        float mn = fmaxf(m, a);
        float corr = __expf(m - mn);
        float w = __expf(a - mn);
        float4 v4 = edge_val(e0);
        acc.x = fmaf(w, v4.x, acc.x * corr);
        acc.y = fmaf(w, v4.y, acc.y * corr);
        acc.z = fmaf(w, v4.z, acc.z * corr);
        acc.w = fmaf(w, v4.w, acc.w * corr);
        l = fmaf(l, corr, w);
        m = mn;
    }
    float inv = (l > 0.f) ? 1.f / l : 0.f;
    float4 hv;
    hv.x = fmaxf(acc.x * inv + s4.x, 0.f);
    hv.y = fmaxf(acc.y * inv + s4.y, 0.f);
    hv.z = fmaxf(acc.z * inv + s4.z, 0.f);
    hv.w = fmaxf(acc.w * inv + s4.w, 0.f);
    if (hf) *(float4*)(hf + (size_t)dst * H + (i16 << 2)) = hv;
    if (gW) {
        float4 g4 = *(const float4*)(gW + (i16 << 2));
        float p = hv.x * g4.x + hv.y * g4.y + hv.z * g4.z + hv.w * g4.w;
        p = radd16(p);
        if (i16 == 0) gate[dst] = p + gb[0];
    }
    if (wbn) {
        // stage the block's 16 fresh h rows as bf16, then 8 MFMA/wave -> next qkv
        uint2 hp;
        hp.x = f2bf(hv.x) | (f2bf(hv.y) << 16);
        hp.y = f2bf(hv.z) | (f2bf(hv.w) << 16);
        *(uint2*)(hs16 + (((wave * 4 + g) << 6) + (i16 << 2))) = hp;
        __syncthreads();
        int n16 = lane & 15, quad = lane >> 4;
        f32x4 oacc[4];
        #pragma unroll
        for (int i = 0; i < 4; i++) oacc[i] = (f32x4){0.f, 0.f, 0.f, 0.f};
        #pragma unroll
        for (int kb = 0; kb < 2; kb++) {
            bf16x8 afr = *(const bf16x8*)(hs16 + ((n16 << 6) + kb * 32 + quad * 8));
            #pragma unroll
            for (int mat = 0; mat < 4; mat++) {
                int ct = mat * 4 + wave;
                const bf16x8* bp = (const bf16x8*)(wbn + (((kb * 4 + quad) << 11) + ((ct * 16 + n16) << 3)));
                oacc[mat] = __builtin_amdgcn_mfma_f32_16x16x32_bf16(afr, *bp, oacc[mat], 0, 0, 0);
            }
        }
        int col = (wave << 4) + n16;
        float bQ = bqn[col], bK = bkn[col], bV = bvn[col], bS = bsn[col];
        int nb = blockIdx.x * 16 + quad * 4;
        #pragma unroll
        for (int r = 0; r < 4; r++) {
            qs_out[(size_t)(nb + r) * 64 + col] = f2bf(oacc[0][r] + bQ) | (f2bf(oacc[3][r] + bS) << 16);
            kv_out[(size_t)(nb + r) * 64 + col] = f2bf(oacc[2][r] + bV) | (f2bf(oacc[1][r] + bK) << 16);
        }
    }
}

// ---------------- fused per-graph readout (W column in registers) ----------------
__global__ __launch_bounds__(256) void k_readout2(
    const float* __restrict__ h, const float* __restrict__ oW,
    const float* __restrict__ ob, const float* __restrict__ gate,
    const int* __restrict__ gs, float* __restrict__ out)
{
    __shared__ float hs[8][H + 1];
    __shared__ float red[256];
    __shared__ float den_s[8];
    __shared__ float gmax_s, den_tot;
    int t = threadIdx.x;
    int g = blockIdx.x;
    int ln = t >> 5, o = t & 31;
    float wreg[H];
    #pragma unroll
    for (int i = 0; i < H; i++) wreg[i] = oW[i * OUTD + o];
    int beg = gs[g], end = gs[g + 1];
    float mx = -INFINITY;
    for (int n = beg + t; n < end; n += 256) mx = fmaxf(mx, gate[n]);
    red[t] = mx;
    __syncthreads();
    for (int sft = 128; sft > 0; sft >>= 1) {
        if (t < sft) red[t] = fmaxf(red[t], red[t + sft]);
        __syncthreads();
    }
    if (t == 0) gmax_s = red[0];
    __syncthreads();
    float gm = gmax_s;
    float acc = 0.f, den = 0.f;
    for (int n0 = beg; n0 < end; n0 += 8) {
        __syncthreads();
        for (int i = t; i < 8 * H; i += 256) {
            int r = i >> 6, c = i & 63;
            int n = n0 + r;
            hs[r][c] = (n < end) ? h[(size_t)n * H + c] : 0.f;
        }
        __syncthreads();
        int n = n0 + ln;
        if (n < end) {
            float wt = __expf(gate[n] - gm);
            float d0 = 0.f;
            #pragma unroll
            for (int i = 0; i < H; i++) d0 += hs[ln][i] * wreg[i];
            acc += wt * d0;
            if (o == 0) den += wt;
        }
    }
    __syncthreads();
    red[t] = acc;
    if (o == 0) den_s[ln] = den;
    __syncthreads();
    for (int sft = 4; sft >= 1; sft >>= 1) {
        if (ln < sft) red[t] += red[t + sft * 32];
        __syncthreads();
    }
    if (t == 0) {
        float dt = 0.f;
        #pragma unroll
        for (int i = 0; i < 8; i++) dt += den_s[i];
        den_tot = dt;
    }
    __syncthreads();
    if (ln == 0) {
        float dt = den_tot;
        out[g * OUTD + o] = (dt > 0.f) ? red[o] / dt + ob[o] : 0.f;
    }
}

extern "C" void kernel_launch(void* const* d_in, const int* in_sizes, int n_in,
                              void* d_out, int out_size, void* d_ws, size_t ws_size,
                              hipStream_t stream)
{
    const int* x        = (const int*)d_in[0];
    const int* ei       = (const int*)d_in[1];
    const int* ea       = (const int*)d_in[2];
    const int* batch    = (const int*)d_in[3];
    const float* node_emb = (const float*)d_in[4];
    const float* edge_emb = (const float*)d_in[5];
    const float* Wq    = (const float*)d_in[6];
    const float* Wk    = (const float*)d_in[7];
    const float* Wv    = (const float*)d_in[8];
    const float* We    = (const float*)d_in[9];
    const float* Wskip = (const float*)d_in[10];
    const float* bq    = (const float*)d_in[11];
    const float* bk    = (const float*)d_in[12];
    const float* bv    = (const float*)d_in[13];
    const float* bskip = (const float*)d_in[14];
    const float* gate_W = (const float*)d_in[15];
    const float* gate_b = (const float*)d_in[16];
    const float* out_W  = (const float*)d_in[17];
    const float* out_b  = (const float*)d_in[18];
    float* out = (float*)d_out;

    const size_t NH = (size_t)N_NODES * H;       // 3,200,000
    float* ws   = (float*)d_ws;
    unsigned* qs_a = (unsigned*)ws;              // qkv buffer A (layers 0,2)
    unsigned* kv_a = qs_a + NH;
    unsigned* qs_b = kv_a + NH;                  // qkv buffer B (layer 1)
    unsigned* kv_b = qs_b + NH;
    float* hf32 = (float*)(kv_b + NH);           // fp32 h (final layer only)
    float* te   = hf32 + NH;                     // LAYERS*10*64 = 1920
    float* gate = te + LAYERS * 10 * H;
    int* row_start = (int*)(gate + N_NODES);
    int* row_end   = row_start + N_NODES;
    int* packed    = row_end + N_NODES;          // final CSR edge packets
    int* pmid      = packed + N_EDGES;           // bucket-sorted intermediate
    int* hist      = pmid + N_EDGES;             // NBUCK * NB_HISTB ([bucket][block])
    int* tot       = hist + NBUCK * NB_HISTB;    // NBUCK bucket totals
    int* gs        = tot + NBUCK;                // 257 ints
    unsigned* tqs  = (unsigned*)(gs + NGRAPH + 1);   // 42*64 layer-0 q|s table
    unsigned* tkv  = tqs + FB_TAB * 64;              // 42*64 layer-0 v|k table
    ushort_t* wb16 = (ushort_t*)(tkv + FB_TAB * 64); // 3*16384 bf16 weights (chunk-major)

    k_front<<<NB_FRONT, 256, 0, stream>>>(x, node_emb, edge_emb, We, te, ei, hist, batch, gs,
                                          Wq, Wk, Wv, Wskip, bq, bk, bv, bskip, wb16, tqs, tkv);
    k_scan_gather<<<NB_GATHER + NB_SCAN, 256, 0, stream>>>(x, tqs, tkv, qs_a, kv_a, hist, tot);
    k_scatter<<<NB_HISTB, 256, 0, stream>>>(ei, ea, hist, tot, pmid);
    k_final<<<NBUCK, 256, 0, stream>>>(pmid, tot, packed, row_start, row_end);

    // layer 0: read A, epilogue gemm (wb layer 1) -> B
    k_agg<<<NB_AGG, 256, 0, stream>>>(
        row_start, row_end, packed, qs_a, kv_a, te,
        wb16 + (size_t)1 * 16384, bq + H, bk + H, bv + H, bskip + H, qs_b, kv_b,
        nullptr, nullptr, nullptr, nullptr);
    // layer 1: read B, epilogue gemm (wb layer 2) -> A
    k_agg<<<NB_AGG, 256, 0, stream>>>(
        row_start, row_end, packed, qs_b, kv_b, te + 10 * H,
        wb16 + (size_t)2 * 16384, bq + 2 * H, bk + 2 * H, bv + 2 * H, bskip + 2 * H, qs_a, kv_a,
        nullptr, nullptr, nullptr, nullptr);
    // layer 2: read A, write fp32 h + gate
    k_agg<<<NB_AGG, 256, 0, stream>>>(
        row_start, row_end, packed, qs_a, kv_a, te + 2 * 10 * H,
        nullptr, nullptr, nullptr, nullptr, nullptr, nullptr, nullptr,
        hf32, gate_W, gate_b, gate);

    k_readout2<<<NGRAPH, 256, 0, stream>>>(hf32, out_W, out_b, gate, gs, out);
}

// Round 6
// 262.128 us; speedup vs baseline: 1.4447x; 1.0297x over previous
//
#include <hip/hip_runtime.h>
#include <hip/hip_bf16.h>

#define N_NODES 50000
#define N_EDGES 800000
#define H 64
#define ED 32
#define LAYERS 3
#define NGRAPH 256
#define OUTD 32
#define SCALE 0.125f
#define NCAT 42

// bucketed counting sort for CSR build (no global atomics anywhere)
#define BNODES 128                                  // nodes per bucket (dst >> 7)
#define NBUCK 391                                   // ceil(50000/128)
#define NB_HISTB 256                                // histogram / scatter blocks
#define EPB (N_EDGES / NB_HISTB)                    // 3125 edges per block

// fused front-end virtual block ranges
#define FB_HIST 256
#define FB_TE   8
#define FB_GB   2
#define FB_WB   192                                 // 3*16384 bf16 weight fragments / 256
#define FB_TAB  NCAT                                // layer-0 qkv table, 1 block per category
#define NB_FRONT (FB_HIST + FB_TE + FB_GB + FB_WB + FB_TAB)

#define NB_SCAN   98                                // 391 buckets / 4 per block
#define NB_AGG    3125                              // 50000 dsts / 16
#define PKCAP     768                               // staged packets per block (avg 256)

typedef __attribute__((ext_vector_type(8))) short bf16x8;
typedef __attribute__((ext_vector_type(4))) float f32x4;
typedef unsigned short ushort_t;

// fp32 -> bf16 round-to-nearest-even
__device__ __forceinline__ unsigned f2bf(float f) {
    unsigned u = __float_as_uint(f);
    return (u + 0x7FFFu + ((u >> 16) & 1u)) >> 16;
}

// 16-lane all-reduce sum via DPP (VALU only, no LDS pipe).
__device__ __forceinline__ float radd16(float x) {
    x += __int_as_float(__builtin_amdgcn_update_dpp(0, __float_as_int(x), 0xB1, 0xF, 0xF, true));   // quad_perm 1,0,3,2
    x += __int_as_float(__builtin_amdgcn_update_dpp(0, __float_as_int(x), 0x4E, 0xF, 0xF, true));   // quad_perm 2,3,0,1
    x += __int_as_float(__builtin_amdgcn_update_dpp(0, __float_as_int(x), 0x124, 0xF, 0xF, true));  // row_ror:4
    x += __int_as_float(__builtin_amdgcn_update_dpp(0, __float_as_int(x), 0x128, 0xF, 0xF, true));  // row_ror:8
    return x;
}

// shared prologue: exclusive scan of 391 bucket totals -> bst[] in LDS
__device__ __forceinline__ void build_bstart(const int* __restrict__ tot,
                                             int* bst, int* part, int t) {
    int u0 = t * 2, u1 = t * 2 + 1;
    int a0 = (u0 < NBUCK) ? tot[u0] : 0;
    int a1 = (u1 < NBUCK) ? tot[u1] : 0;
    part[t] = a0 + a1;
    __syncthreads();
    for (int off = 1; off < 256; off <<= 1) {
        int add = (t >= off) ? part[t - off] : 0;
        __syncthreads();
        part[t] += add;
        __syncthreads();
    }
    int excl = part[t] - (a0 + a1);
    if (u0 < NBUCK) bst[u0] = excl;
    if (u1 < NBUCK) bst[u1] = excl + a0;
    if (t == 0) bst[NBUCK] = N_EDGES;
    __syncthreads();
}

// ---------------- fused front end: hist | te | gbounds | weights | layer0-table --------
__global__ __launch_bounds__(256) void k_front(
    const int* __restrict__ x, const float* __restrict__ node_emb,
    const float* __restrict__ edge_emb, const float* __restrict__ We, float* __restrict__ te,
    const int* __restrict__ ei, int* __restrict__ hist,
    const int* __restrict__ batch, int* __restrict__ gs,
    const float* __restrict__ Wq, const float* __restrict__ Wk,
    const float* __restrict__ Wv, const float* __restrict__ Wsk,
    const float* __restrict__ bq, const float* __restrict__ bk,
    const float* __restrict__ bv, const float* __restrict__ bsk,
    ushort_t* __restrict__ wb16,
    unsigned* __restrict__ tqs, unsigned* __restrict__ tkv)
{
    __shared__ int lh[NBUCK];
    __shared__ float tb[4][64];
    int b = blockIdx.x, t = threadIdx.x;
    if (b < FB_HIST) {
        // per-block bucket histogram in LDS; transposed writeback hist[bucket][block]
        for (int i = t; i < NBUCK; i += 256) lh[i] = 0;
        __syncthreads();
        const int* dstp = ei + N_EDGES + b * EPB;
        for (int i = t; i < EPB; i += 256)
            atomicAdd(&lh[dstp[i] >> 7], 1);
        __syncthreads();
        for (int i = t; i < NBUCK; i += 256) hist[i * NB_HISTB + b] = lh[i];
    } else if (b < FB_HIST + FB_TE) {
        int i = (b - FB_HIST) * 256 + t;
        if (i < LAYERS * 10 * H) {
            int c = i & 63;
            int cat = (i >> 6) % 10;
            int l = i / (10 * H);
            float acc = 0.f;
            for (int d = 0; d < ED; d++)
                acc += edge_emb[cat * ED + d] * We[((size_t)l * ED + d) * H + c];
            te[i] = acc;
        }
    } else if (b < FB_HIST + FB_TE + FB_GB) {
        int g = (b - FB_HIST - FB_TE) * 256 + t;
        if (g <= NGRAPH) {
            int lo = 0, hi = N_NODES;
            while (lo < hi) {
                int mid = (lo + hi) >> 1;
                if (batch[mid] < g) lo = mid + 1; else hi = mid;
            }
            gs[g] = lo;
        }
    } else if (b < FB_HIST + FB_TE + FB_GB + FB_WB) {
        // chunk-major weight layout: wb16[l][c_id][r][j]  (c_id = kb*4+quad, r = ct*16+n16)
        int g = (b - FB_HIST - FB_TE - FB_GB) * 256 + t;   // < 49152
        int l = g >> 14;
        int rem = g & 16383;
        int c_id = rem >> 11;
        int rr = (rem >> 3) & 255;
        int j = rem & 7;
        int mat = rr >> 6, n = rr & 63;
        int k = ((c_id >> 2) << 5) + ((c_id & 3) << 3) + j;
        const float* Wm = (mat == 0) ? Wq : (mat == 1) ? Wk : (mat == 2) ? Wv : Wsk;
        wb16[g] = (ushort_t)f2bf(Wm[(size_t)l * 4096 + k * 64 + n]);
    } else {
        // layer-0 qkv table: one block per node category, fp32 matvec (exact)
        int cat = b - (FB_HIST + FB_TE + FB_GB + FB_WB);
        int mat = t >> 6, c = t & 63;
        const float* Wm = (mat == 0) ? Wq : (mat == 1) ? Wk : (mat == 2) ? Wv : Wsk;
        const float* bm = (mat == 0) ? bq : (mat == 1) ? bk : (mat == 2) ? bv : bsk;
        float acc = bm[c];
        for (int k = 0; k < H; k++)
            acc += node_emb[cat * H + k] * Wm[k * 64 + c];
        tb[mat][c] = acc;
        __syncthreads();
        if (t < 64) {
            tqs[cat * 64 + t] = f2bf(tb[0][t]) | (f2bf(tb[3][t]) << 16);   // q | skip
            tkv[cat * 64 + t] = f2bf(tb[2][t]) | (f2bf(tb[1][t]) << 16);   // v | k
        }
    }
}

// ---------------- per-bucket block-prefix scan (in-place) ----------------
__global__ __launch_bounds__(256) void k_scan(int* __restrict__ hist, int* __restrict__ tot)
{
    __shared__ int sv[256];
    int sb = blockIdx.x, t = threadIdx.x;
    for (int r = 0; r < 4; r++) {
        int u = sb * 4 + r;
        if (u < NBUCK) {
            int v = hist[u * NB_HISTB + t];
            sv[t] = v;
            __syncthreads();
            for (int off = 1; off < 256; off <<= 1) {
                int add = (t >= off) ? sv[t - off] : 0;
                __syncthreads();
                sv[t] += add;
                __syncthreads();
            }
            int incl = sv[t];
            hist[u * NB_HISTB + t] = incl - v;   // exclusive prefix, in place
            if (t == 255) tot[u] = incl;
            __syncthreads();
        }
    }
}

// ---------------- scatter: rank via LDS atomics against per-block cursors -------------
// packet: src(0..15) | catx(16..24) where catx = cat*42 + x[src] | (dst&127)(25..31)
__global__ __launch_bounds__(256) void k_scatter(
    const int* __restrict__ ei, const int* __restrict__ ea, const int* __restrict__ x,
    const int* __restrict__ hist, const int* __restrict__ tot,
    int* __restrict__ pmid)
{
    __shared__ int bst[NBUCK + 1];
    __shared__ int part[256];
    __shared__ int curS[NBUCK];
    int b = blockIdx.x, t = threadIdx.x;
    build_bstart(tot, bst, part, t);
    for (int u = t; u < NBUCK; u += 256)
        curS[u] = bst[u] + hist[u * NB_HISTB + b];
    __syncthreads();
    int e0 = b * EPB;
    for (int i = t; i < EPB; i += 256) {
        int e = e0 + i;
        int src = ei[e], dst = ei[N_EDGES + e], cat = ea[e];
        int xs = x[src];
        int pos = atomicAdd(&curS[dst >> 7], 1);
        pmid[pos] = src | ((cat * NCAT + xs) << 16) | ((dst & 127) << 25);
    }
}

// ---------------- per-bucket finalize: exact CSR rows + in-bucket ordering -------------
__global__ __launch_bounds__(256) void k_final(
    const int* __restrict__ pmid, const int* __restrict__ tot,
    int* __restrict__ packed, int* __restrict__ row_start, int* __restrict__ row_end)
{
    __shared__ int bst[NBUCK + 1];
    __shared__ int part[256];
    __shared__ int cnt[BNODES];
    __shared__ int scan_s[BNODES];
    int b = blockIdx.x, t = threadIdx.x;
    build_bstart(tot, bst, part, t);
    int beg = bst[b], end = bst[b + 1];
    if (t < BNODES) cnt[t] = 0;
    __syncthreads();
    for (int e = beg + t; e < end; e += 256)
        atomicAdd(&cnt[((unsigned)pmid[e] >> 25) & 127], 1);
    __syncthreads();
    if (t < BNODES) scan_s[t] = cnt[t];
    __syncthreads();
    for (int off = 1; off < BNODES; off <<= 1) {
        int add = (t >= off && t < BNODES) ? scan_s[t - off] : 0;
        __syncthreads();
        if (t < BNODES) scan_s[t] += add;
        __syncthreads();
    }
    if (t < BNODES) {
        int c = cnt[t];
        int excl = scan_s[t] - c;          // exclusive within bucket
        int node = b * BNODES + t;
        if (node < N_NODES) {
            row_start[node] = beg + excl;
            row_end[node] = beg + excl + c;
        }
        cnt[t] = beg + excl;               // reuse as cursor
    }
    __syncthreads();
    for (int e = beg + t; e < end; e += 256) {
        int p = pmid[e];
        int pos = atomicAdd(&cnt[((unsigned)p >> 25) & 127], 1);
        packed[pos] = p & 0x1FFFFFF;       // src | catx<<16
    }
}

// per-edge load bundle
struct EdgeLd { uint4 kv; float4 t; };
__device__ __forceinline__ float edge_dot(const EdgeLd& e, const float4& q4) {
    float p;
    p = (__uint_as_float(e.kv.x & 0xFFFF0000u) + e.t.x) * q4.x;
    p = fmaf(__uint_as_float(e.kv.y & 0xFFFF0000u) + e.t.y, q4.y, p);
    p = fmaf(__uint_as_float(e.kv.z & 0xFFFF0000u) + e.t.z, q4.z, p);
    p = fmaf(__uint_as_float(e.kv.w & 0xFFFF0000u) + e.t.w, q4.w, p);
    return radd16(p) * SCALE;
}
__device__ __forceinline__ float4 edge_val(const EdgeLd& e) {
    float4 v;
    v.x = __uint_as_float(e.kv.x << 16) + e.t.x;
    v.y = __uint_as_float(e.kv.y << 16) + e.t.y;
    v.z = __uint_as_float(e.kv.z << 16) + e.t.z;
    v.w = __uint_as_float(e.kv.w << 16) + e.t.w;
    return v;
}

// ---------------- fused gather-attention + next-layer qkv GEMM epilogue --------------
// MODE 0: layer 0 — k/v/q from 42-entry LDS tables (no global qkv), epilogue gemm
// MODE 1: mid layer — global qkv in, epilogue gemm
// MODE 2: last layer — global qkv in, write fp32 h + gate
template<int MODE>
__device__ __forceinline__ void agg_body(
    const int* __restrict__ row_start, const int* __restrict__ row_end,
    const int* __restrict__ packed, const int* __restrict__ x,
    const unsigned* __restrict__ qs_in, const unsigned* __restrict__ kv_in,
    const unsigned* __restrict__ tqs, const unsigned* __restrict__ tkv,
    const float* __restrict__ te,
    const ushort_t* __restrict__ wbn, const float* __restrict__ bqn,
    const float* __restrict__ bkn, const float* __restrict__ bvn,
    const float* __restrict__ bsn,
    unsigned* __restrict__ qs_out, unsigned* __restrict__ kv_out,
    float* __restrict__ hf, const float* __restrict__ gW,
    const float* __restrict__ gb, float* __restrict__ gate,
    float* tel, unsigned* tqsl, unsigned* tkvl, ushort_t* hs16, int* pkl)
{
    int t = threadIdx.x, bid = blockIdx.x;
    int wave = t >> 6, lane = t & 63;
    int g = lane >> 4, i16 = lane & 15;
    int dst = bid * 16 + wave * 4 + g;
    int beg = row_start[dst], end = row_end[dst];
    int beg0 = row_start[bid * 16];
    int cnt = row_end[bid * 16 + 15] - beg0;
    bool use_lds = (cnt <= PKCAP);
    for (int i = t; i < 640; i += 256) tel[i] = te[i];
    if constexpr (MODE == 0) {
        for (int i = t; i < NCAT * 64; i += 256) { tqsl[i] = tqs[i]; tkvl[i] = tkv[i]; }
    }
    if (use_lds) for (int i = t; i < cnt; i += 256) pkl[i] = packed[beg0 + i];
    uint4 uq = {0u, 0u, 0u, 0u};
    if constexpr (MODE != 0)
        uq = *(const uint4*)(qs_in + (size_t)dst * 64 + (i16 << 2));
    __syncthreads();
    if constexpr (MODE == 0) {
        int xd = x[dst];
        uq = *(const uint4*)(tqsl + (xd << 6) + (i16 << 2));
    }
    float4 q4, s4;
    q4.x = __uint_as_float(uq.x << 16); s4.x = __uint_as_float(uq.x & 0xFFFF0000u);
    q4.y = __uint_as_float(uq.y << 16); s4.y = __uint_as_float(uq.y & 0xFFFF0000u);
    q4.z = __uint_as_float(uq.z << 16); s4.z = __uint_as_float(uq.z & 0xFFFF0000u);
    q4.w = __uint_as_float(uq.w << 16); s4.w = __uint_as_float(uq.w & 0xFFFF0000u);
    float m = -1e30f, l = 0.f;
    float4 acc = {0.f, 0.f, 0.f, 0.f};

    auto eload = [&](int pkt) {
        EdgeLd r;
        unsigned catx = ((unsigned)pkt >> 16) & 0x1FFu;
        int cat = (int)((catx * 1561u) >> 16);        // catx / 42
        r.t = *(const float4*)(tel + (cat << 6) + (i16 << 2));
        if constexpr (MODE == 0) {
            int xc = (int)catx - cat * NCAT;
            r.kv = *(const uint4*)(tkvl + (xc << 6) + (i16 << 2));
        } else {
            int src = pkt & 0xFFFF;
            r.kv = *(const uint4*)(kv_in + ((size_t)src << 6) + (i16 << 2));
        }
        return r;
    };
    auto run = [&](auto PKT) {
        int e = beg;
        for (; e + 3 < end; e += 4) {
            int p0 = PKT(e), p1 = PKT(e + 1), p2 = PKT(e + 2), p3 = PKT(e + 3);
            EdgeLd e0 = eload(p0), e1 = eload(p1), e2 = eload(p2), e3 = eload(p3);
            float a0 = edge_dot(e0, q4), a1 = edge_dot(e1, q4);
            float a2 = edge_dot(e2, q4), a3 = edge_dot(e3, q4);
            float mn = fmaxf(m, fmaxf(fmaxf(a0, a1), fmaxf(a2, a3)));
            float corr = __expf(m - mn);
            float w0 = __expf(a0 - mn), w1 = __expf(a1 - mn);
            float w2 = __expf(a2 - mn), w3 = __expf(a3 - mn);
            float4 v0 = edge_val(e0), v1 = edge_val(e1), v2 = edge_val(e2), v3 = edge_val(e3);
            acc.x = fmaf(w0, v0.x, fmaf(w1, v1.x, fmaf(w2, v2.x, fmaf(w3, v3.x, acc.x * corr))));
            acc.y = fmaf(w0, v0.y, fmaf(w1, v1.y, fmaf(w2, v2.y, fmaf(w3, v3.y, acc.y * corr))));
            acc.z = fmaf(w0, v0.z, fmaf(w1, v1.z, fmaf(w2, v2.z, fmaf(w3, v3.z, acc.z * corr))));
            acc.w = fmaf(w0, v0.w, fmaf(w1, v1.w, fmaf(w2, v2.w, fmaf(w3, v3.w, acc.w * corr))));
            l = fmaf(l, corr, (w0 + w1) + (w2 + w3));
            m = mn;
        }
        for (; e < end; e++) {
            EdgeLd e0 = eload(PKT(e));
            float a = edge_dot(e0, q4);
            float mn = fmaxf(m, a);
            float corr = __expf(m - mn);
            float w = __expf(a - mn);
            float4 v4 = edge_val(e0);
            acc.x = fmaf(w, v4.x, acc.x * corr);
            acc.y = fmaf(w, v4.y, acc.y * corr);
            acc.z = fmaf(w, v4.z, acc.z * corr);
            acc.w = fmaf(w, v4.w, acc.w * corr);
            l = fmaf(l, corr, w);
            m = mn;
        }
    };
    if (use_lds) run([&](int e) { return pkl[e - beg0]; });
    else         run([&](int e) { return packed[e]; });

    float inv = (l > 0.f) ? 1.f / l : 0.f;
    float4 hv;
    hv.x = fmaxf(acc.x * inv + s4.x, 0.f);
    hv.y = fmaxf(acc.y * inv + s4.y, 0.f);
    hv.z = fmaxf(acc.z * inv + s4.z, 0.f);
    hv.w = fmaxf(acc.w * inv + s4.w, 0.f);
    if constexpr (MODE == 2) {
        *(float4*)(hf + (size_t)dst * H + (i16 << 2)) = hv;
        float4 g4 = *(const float4*)(gW + (i16 << 2));
        float p = hv.x * g4.x + hv.y * g4.y + hv.z * g4.z + hv.w * g4.w;
        p = radd16(p);
        if (i16 == 0) gate[dst] = p + gb[0];
    } else {
        // stage the block's 16 fresh h rows as bf16, then 8 MFMA/wave -> next qkv
        uint2 hp;
        hp.x = f2bf(hv.x) | (f2bf(hv.y) << 16);
        hp.y = f2bf(hv.z) | (f2bf(hv.w) << 16);
        *(uint2*)(hs16 + (((wave * 4 + g) << 6) + (i16 << 2))) = hp;
        __syncthreads();
        int n16 = lane & 15, quad = lane >> 4;
        f32x4 oacc[4];
        #pragma unroll
        for (int i = 0; i < 4; i++) oacc[i] = (f32x4){0.f, 0.f, 0.f, 0.f};
        #pragma unroll
        for (int kb = 0; kb < 2; kb++) {
            bf16x8 afr = *(const bf16x8*)(hs16 + ((n16 << 6) + kb * 32 + quad * 8));
            #pragma unroll
            for (int mat = 0; mat < 4; mat++) {
                int ct = mat * 4 + wave;
                const bf16x8* bp = (const bf16x8*)(wbn + (((kb * 4 + quad) << 11) + ((ct * 16 + n16) << 3)));
                oacc[mat] = __builtin_amdgcn_mfma_f32_16x16x32_bf16(afr, *bp, oacc[mat], 0, 0, 0);
            }
        }
        int col = (wave << 4) + n16;
        float bQ = bqn[col], bK = bkn[col], bV = bvn[col], bS = bsn[col];
        int nb = bid * 16 + quad * 4;
        #pragma unroll
        for (int r = 0; r < 4; r++) {
            qs_out[(size_t)(nb + r) * 64 + col] = f2bf(oacc[0][r] + bQ) | (f2bf(oacc[3][r] + bS) << 16);
            kv_out[(size_t)(nb + r) * 64 + col] = f2bf(oacc[2][r] + bV) | (f2bf(oacc[1][r] + bK) << 16);
        }
    }
}

__global__ __launch_bounds__(256, 4) void k_agg0(
    const int* __restrict__ row_start, const int* __restrict__ row_end,
    const int* __restrict__ packed, const int* __restrict__ x,
    const unsigned* __restrict__ tqs, const unsigned* __restrict__ tkv,
    const float* __restrict__ te,
    const ushort_t* __restrict__ wbn, const float* __restrict__ bqn,
    const float* __restrict__ bkn, const float* __restrict__ bvn,
    const float* __restrict__ bsn,
    unsigned* __restrict__ qs_out, unsigned* __restrict__ kv_out)
{
    __shared__ float tel[640];
    __shared__ unsigned tqsl[NCAT * 64];
    __shared__ unsigned tkvl[NCAT * 64];
    __shared__ ushort_t hs16[1024];
    __shared__ int pkl[PKCAP];
    agg_body<0>(row_start, row_end, packed, x, nullptr, nullptr, tqs, tkv, te,
                wbn, bqn, bkn, bvn, bsn, qs_out, kv_out,
                nullptr, nullptr, nullptr, nullptr, tel, tqsl, tkvl, hs16, pkl);
}

__global__ __launch_bounds__(256, 4) void k_agg1(
    const int* __restrict__ row_start, const int* __restrict__ row_end,
    const int* __restrict__ packed,
    const unsigned* __restrict__ qs_in, const unsigned* __restrict__ kv_in,
    const float* __restrict__ te,
    const ushort_t* __restrict__ wbn, const float* __restrict__ bqn,
    const float* __restrict__ bkn, const float* __restrict__ bvn,
    const float* __restrict__ bsn,
    unsigned* __restrict__ qs_out, unsigned* __restrict__ kv_out)
{
    __shared__ float tel[640];
    __shared__ ushort_t hs16[1024];
    __shared__ int pkl[PKCAP];
    agg_body<1>(row_start, row_end, packed, nullptr, qs_in, kv_in, nullptr, nullptr, te,
                wbn, bqn, bkn, bvn, bsn, qs_out, kv_out,
                nullptr, nullptr, nullptr, nullptr, tel, nullptr, nullptr, hs16, pkl);
}

__global__ __launch_bounds__(256, 4) void k_agg2(
    const int* __restrict__ row_start, const int* __restrict__ row_end,
    const int* __restrict__ packed,
    const unsigned* __restrict__ qs_in, const unsigned* __restrict__ kv_in,
    const float* __restrict__ te,
    float* __restrict__ hf, const float* __restrict__ gW,
    const float* __restrict__ gb, float* __restrict__ gate)
{
    __shared__ float tel[640];
    __shared__ int pkl[PKCAP];
    agg_body<2>(row_start, row_end, packed, nullptr, qs_in, kv_in, nullptr, nullptr, te,
                nullptr, nullptr, nullptr, nullptr, nullptr, nullptr, nullptr,
                hf, gW, gb, gate, tel, nullptr, nullptr, nullptr, pkl);
}

// ---------------- fused per-graph readout (W column in registers) ----------------
__global__ __launch_bounds__(256) void k_readout2(
    const float* __restrict__ h, const float* __restrict__ oW,
    const float* __restrict__ ob, const float* __restrict__ gate,
    const int* __restrict__ gs, float* __restrict__ out)
{
    __shared__ float hs[8][H + 1];
    __shared__ float red[256];
    __shared__ float den_s[8];
    __shared__ float gmax_s, den_tot;
    int t = threadIdx.x;
    int g = blockIdx.x;
    int ln = t >> 5, o = t & 31;
    float wreg[H];
    #pragma unroll
    for (int i = 0; i < H; i++) wreg[i] = oW[i * OUTD + o];
    int beg = gs[g], end = gs[g + 1];
    float mx = -INFINITY;
    for (int n = beg + t; n < end; n += 256) mx = fmaxf(mx, gate[n]);
    red[t] = mx;
    __syncthreads();
    for (int sft = 128; sft > 0; sft >>= 1) {
        if (t < sft) red[t] = fmaxf(red[t], red[t + sft]);
        __syncthreads();
    }
    if (t == 0) gmax_s = red[0];
    __syncthreads();
    float gm = gmax_s;
    float acc = 0.f, den = 0.f;
    for (int n0 = beg; n0 < end; n0 += 8) {
        __syncthreads();
        for (int i = t; i < 8 * H; i += 256) {
            int r = i >> 6, c = i & 63;
            int n = n0 + r;
            hs[r][c] = (n < end) ? h[(size_t)n * H + c] : 0.f;
        }
        __syncthreads();
        int n = n0 + ln;
        if (n < end) {
            float wt = __expf(gate[n] - gm);
            float d0 = 0.f;
            #pragma unroll
            for (int i = 0; i < H; i++) d0 += hs[ln][i] * wreg[i];
            acc += wt * d0;
            if (o == 0) den += wt;
        }
    }
    __syncthreads();
    red[t] = acc;
    if (o == 0) den_s[ln] = den;
    __syncthreads();
    for (int sft = 4; sft >= 1; sft >>= 1) {
        if (ln < sft) red[t] += red[t + sft * 32];
        __syncthreads();
    }
    if (t == 0) {
        float dt = 0.f;
        #pragma unroll
        for (int i = 0; i < 8; i++) dt += den_s[i];
        den_tot = dt;
    }
    __syncthreads();
    if (ln == 0) {
        float dt = den_tot;
        out[g * OUTD + o] = (dt > 0.f) ? red[o] / dt + ob[o] : 0.f;
    }
}

extern "C" void kernel_launch(void* const* d_in, const int* in_sizes, int n_in,
                              void* d_out, int out_size, void* d_ws, size_t ws_size,
                              hipStream_t stream)
{
    const int* x        = (const int*)d_in[0];
    const int* ei       = (const int*)d_in[1];
    const int* ea       = (const int*)d_in[2];
    const int* batch    = (const int*)d_in[3];
    const float* node_emb = (const float*)d_in[4];
    const float* edge_emb = (const float*)d_in[5];
    const float* Wq    = (const float*)d_in[6];
    const float* Wk    = (const float*)d_in[7];
    const float* Wv    = (const float*)d_in[8];
    const float* We    = (const float*)d_in[9];
    const float* Wskip = (const float*)d_in[10];
    const float* bq    = (const float*)d_in[11];
    const float* bk    = (const float*)d_in[12];
    const float* bv    = (const float*)d_in[13];
    const float* bskip = (const float*)d_in[14];
    const float* gate_W = (const float*)d_in[15];
    const float* gate_b = (const float*)d_in[16];
    const float* out_W  = (const float*)d_in[17];
    const float* out_b  = (const float*)d_in[18];
    float* out = (float*)d_out;

    const size_t NH = (size_t)N_NODES * H;       // 3,200,000
    float* ws   = (float*)d_ws;
    unsigned* qs_a = (unsigned*)ws;              // layer-1 qkv (written by agg0)
    unsigned* kv_a = qs_a + NH;
    unsigned* qs_b = kv_a + NH;                  // layer-2 qkv (written by agg1)
    unsigned* kv_b = qs_b + NH;
    float* hf32 = (float*)(kv_b + NH);           // fp32 h (final layer only)
    float* te   = hf32 + NH;                     // LAYERS*10*64 = 1920
    float* gate = te + LAYERS * 10 * H;
    int* row_start = (int*)(gate + N_NODES);
    int* row_end   = row_start + N_NODES;
    int* packed    = row_end + N_NODES;          // final CSR edge packets
    int* pmid      = packed + N_EDGES;           // bucket-sorted intermediate
    int* hist      = pmid + N_EDGES;             // NBUCK * NB_HISTB ([bucket][block])
    int* tot       = hist + NBUCK * NB_HISTB;    // NBUCK bucket totals
    int* gs        = tot + NBUCK;                // 257 ints
    unsigned* tqs  = (unsigned*)(gs + NGRAPH + 1);   // 42*64 layer-0 q|s table
    unsigned* tkv  = tqs + FB_TAB * 64;              // 42*64 layer-0 v|k table
    ushort_t* wb16 = (ushort_t*)(tkv + FB_TAB * 64); // 3*16384 bf16 weights (chunk-major)

    k_front<<<NB_FRONT, 256, 0, stream>>>(x, node_emb, edge_emb, We, te, ei, hist, batch, gs,
                                          Wq, Wk, Wv, Wskip, bq, bk, bv, bskip, wb16, tqs, tkv);
    k_scan<<<NB_SCAN, 256, 0, stream>>>(hist, tot);
    k_scatter<<<NB_HISTB, 256, 0, stream>>>(ei, ea, x, hist, tot, pmid);
    k_final<<<NBUCK, 256, 0, stream>>>(pmid, tot, packed, row_start, row_end);

    // layer 0: table-based input, epilogue gemm (wb layer 1) -> A
    k_agg0<<<NB_AGG, 256, 0, stream>>>(
        row_start, row_end, packed, x, tqs, tkv, te,
        wb16 + (size_t)1 * 16384, bq + H, bk + H, bv + H, bskip + H, qs_a, kv_a);
    // layer 1: read A, epilogue gemm (wb layer 2) -> B
    k_agg1<<<NB_AGG, 256, 0, stream>>>(
        row_start, row_end, packed, qs_a, kv_a, te + 10 * H,
        wb16 + (size_t)2 * 16384, bq + 2 * H, bk + 2 * H, bv + 2 * H, bskip + 2 * H, qs_b, kv_b);
    // layer 2: read B, write fp32 h + gate
    k_agg2<<<NB_AGG, 256, 0, stream>>>(
        row_start, row_end, packed, qs_b, kv_b, te + 2 * 10 * H,
        hf32, gate_W, gate_b, gate);

    k_readout2<<<NGRAPH, 256, 0, stream>>>(hf32, out_W, out_b, gate, gs, out);
}

// Round 8
// 256.240 us; speedup vs baseline: 1.4779x; 1.0230x over previous
//
#include <hip/hip_runtime.h>
#include <hip/hip_bf16.h>

#define N_NODES 50000
#define N_EDGES 800000
#define H 64
#define ED 32
#define LAYERS 3
#define NGRAPH 256
#define OUTD 32
#define SCALE 0.125f
#define NCAT 42

// bucketed counting sort for CSR build (no global atomics anywhere)
#define BNODES 128                                  // nodes per bucket (dst >> 7)
#define NBUCK 391                                   // ceil(50000/128)
#define NB_HISTB 256                                // histogram / scatter blocks
#define EPB (N_EDGES / NB_HISTB)                    // 3125 edges per block

// fused front-end virtual block ranges
#define FB_HIST 256
#define FB_TE   8
#define FB_GB   2
#define FB_WB   192                                 // 3*16384 bf16 weight fragments / 256
#define FB_TAB  NCAT                                // layer-0 qkv table, 1 block per category
#define NB_FRONT (FB_HIST + FB_TE + FB_GB + FB_WB + FB_TAB)

#define NB_SCAN   98                                // 391 buckets / 4 per block
#define NB_AGG    3125                              // 50000 dsts / 16
#define PKCAP     768                               // staged packets per block (avg 256)

typedef __attribute__((ext_vector_type(8))) short bf16x8;
typedef __attribute__((ext_vector_type(4))) float f32x4;
typedef unsigned short ushort_t;

// fp32 -> bf16 round-to-nearest-even
__device__ __forceinline__ unsigned f2bf(float f) {
    unsigned u = __float_as_uint(f);
    return (u + 0x7FFFu + ((u >> 16) & 1u)) >> 16;
}

// 16-lane all-reduce sum via DPP (VALU only, no LDS pipe).
__device__ __forceinline__ float radd16(float x) {
    x += __int_as_float(__builtin_amdgcn_update_dpp(0, __float_as_int(x), 0xB1, 0xF, 0xF, true));   // quad_perm 1,0,3,2
    x += __int_as_float(__builtin_amdgcn_update_dpp(0, __float_as_int(x), 0x4E, 0xF, 0xF, true));   // quad_perm 2,3,0,1
    x += __int_as_float(__builtin_amdgcn_update_dpp(0, __float_as_int(x), 0x124, 0xF, 0xF, true));  // row_ror:4
    x += __int_as_float(__builtin_amdgcn_update_dpp(0, __float_as_int(x), 0x128, 0xF, 0xF, true));  // row_ror:8
    return x;
}

// shared prologue: exclusive scan of 391 bucket totals -> bst[] in LDS
__device__ __forceinline__ void build_bstart(const int* __restrict__ tot,
                                             int* bst, int* part, int t) {
    int u0 = t * 2, u1 = t * 2 + 1;
    int a0 = (u0 < NBUCK) ? tot[u0] : 0;
    int a1 = (u1 < NBUCK) ? tot[u1] : 0;
    part[t] = a0 + a1;
    __syncthreads();
    for (int off = 1; off < 256; off <<= 1) {
        int add = (t >= off) ? part[t - off] : 0;
        __syncthreads();
        part[t] += add;
        __syncthreads();
    }
    int excl = part[t] - (a0 + a1);
    if (u0 < NBUCK) bst[u0] = excl;
    if (u1 < NBUCK) bst[u1] = excl + a0;
    if (t == 0) bst[NBUCK] = N_EDGES;
    __syncthreads();
}

// ---------------- fused front end: hist | te | gbounds | weights | layer0-table --------
__global__ __launch_bounds__(256) void k_front(
    const int* __restrict__ x, const float* __restrict__ node_emb,
    const float* __restrict__ edge_emb, const float* __restrict__ We, float* __restrict__ te,
    const int* __restrict__ ei, int* __restrict__ hist,
    const int* __restrict__ batch, int* __restrict__ gs,
    const float* __restrict__ Wq, const float* __restrict__ Wk,
    const float* __restrict__ Wv, const float* __restrict__ Wsk,
    const float* __restrict__ bq, const float* __restrict__ bk,
    const float* __restrict__ bv, const float* __restrict__ bsk,
    ushort_t* __restrict__ wb16,
    unsigned* __restrict__ tqs, unsigned* __restrict__ tkv)
{
    __shared__ int lh[NBUCK];
    __shared__ float tb[4][64];
    int b = blockIdx.x, t = threadIdx.x;
    if (b < FB_HIST) {
        // per-block bucket histogram in LDS; transposed writeback hist[bucket][block]
        for (int i = t; i < NBUCK; i += 256) lh[i] = 0;
        __syncthreads();
        const int* dstp = ei + N_EDGES + b * EPB;
        for (int i = t; i < EPB; i += 256)
            atomicAdd(&lh[dstp[i] >> 7], 1);
        __syncthreads();
        for (int i = t; i < NBUCK; i += 256) hist[i * NB_HISTB + b] = lh[i];
    } else if (b < FB_HIST + FB_TE) {
        int i = (b - FB_HIST) * 256 + t;
        if (i < LAYERS * 10 * H) {
            int c = i & 63;
            int cat = (i >> 6) % 10;
            int l = i / (10 * H);
            float acc = 0.f;
            for (int d = 0; d < ED; d++)
                acc += edge_emb[cat * ED + d] * We[((size_t)l * ED + d) * H + c];
            te[i] = acc;
        }
    } else if (b < FB_HIST + FB_TE + FB_GB) {
        int g = (b - FB_HIST - FB_TE) * 256 + t;
        if (g <= NGRAPH) {
            int lo = 0, hi = N_NODES;
            while (lo < hi) {
                int mid = (lo + hi) >> 1;
                if (batch[mid] < g) lo = mid + 1; else hi = mid;
            }
            gs[g] = lo;
        }
    } else if (b < FB_HIST + FB_TE + FB_GB + FB_WB) {
        // chunk-major weight layout: wb16[l][c_id][r][j]  (c_id = kb*4+quad, r = ct*16+n16)
        int g = (b - FB_HIST - FB_TE - FB_GB) * 256 + t;   // < 49152
        int l = g >> 14;
        int rem = g & 16383;
        int c_id = rem >> 11;
        int rr = (rem >> 3) & 255;
        int j = rem & 7;
        int mat = rr >> 6, n = rr & 63;
        int k = ((c_id >> 2) << 5) + ((c_id & 3) << 3) + j;
        const float* Wm = (mat == 0) ? Wq : (mat == 1) ? Wk : (mat == 2) ? Wv : Wsk;
        wb16[g] = (ushort_t)f2bf(Wm[(size_t)l * 4096 + k * 64 + n]);
    } else {
        // layer-0 qkv table: one block per node category, fp32 matvec (exact)
        int cat = b - (FB_HIST + FB_TE + FB_GB + FB_WB);
        int mat = t >> 6, c = t & 63;
        const float* Wm = (mat == 0) ? Wq : (mat == 1) ? Wk : (mat == 2) ? Wv : Wsk;
        const float* bm = (mat == 0) ? bq : (mat == 1) ? bk : (mat == 2) ? bv : bsk;
        float acc = bm[c];
        for (int k = 0; k < H; k++)
            acc += node_emb[cat * H + k] * Wm[k * 64 + c];
        tb[mat][c] = acc;
        __syncthreads();
        if (t < 64) {
            tqs[cat * 64 + t] = f2bf(tb[0][t]) | (f2bf(tb[3][t]) << 16);   // q | skip
            tkv[cat * 64 + t] = f2bf(tb[2][t]) | (f2bf(tb[1][t]) << 16);   // v | k
        }
    }
}

// ---------------- per-bucket block-prefix scan (in-place) ----------------
__global__ __launch_bounds__(256) void k_scan(int* __restrict__ hist, int* __restrict__ tot)
{
    __shared__ int sv[256];
    int sb = blockIdx.x, t = threadIdx.x;
    for (int r = 0; r < 4; r++) {
        int u = sb * 4 + r;
        if (u < NBUCK) {
            int v = hist[u * NB_HISTB + t];
            sv[t] = v;
            __syncthreads();
            for (int off = 1; off < 256; off <<= 1) {
                int add = (t >= off) ? sv[t - off] : 0;
                __syncthreads();
                sv[t] += add;
                __syncthreads();
            }
            int incl = sv[t];
            hist[u * NB_HISTB + t] = incl - v;   // exclusive prefix, in place
            if (t == 255) tot[u] = incl;
            __syncthreads();
        }
    }
}

// ---------------- scatter: rank via LDS atomics against per-block cursors -------------
// packet: src(0..15) | catx(16..24) where catx = cat*42 + x[src] | (dst&127)(25..31)
__global__ __launch_bounds__(256) void k_scatter(
    const int* __restrict__ ei, const int* __restrict__ ea, const int* __restrict__ x,
    const int* __restrict__ hist, const int* __restrict__ tot,
    int* __restrict__ pmid)
{
    __shared__ int bst[NBUCK + 1];
    __shared__ int part[256];
    __shared__ int curS[NBUCK];
    int b = blockIdx.x, t = threadIdx.x;
    build_bstart(tot, bst, part, t);
    for (int u = t; u < NBUCK; u += 256)
        curS[u] = bst[u] + hist[u * NB_HISTB + b];
    __syncthreads();
    int e0 = b * EPB;
    for (int i = t; i < EPB; i += 256) {
        int e = e0 + i;
        int src = ei[e], dst = ei[N_EDGES + e], cat = ea[e];
        int xs = x[src];
        int pos = atomicAdd(&curS[dst >> 7], 1);
        pmid[pos] = src | ((cat * NCAT + xs) << 16) | ((dst & 127) << 25);
    }
}

// ---------------- per-bucket finalize: exact CSR rows + in-bucket ordering -------------
__global__ __launch_bounds__(256) void k_final(
    const int* __restrict__ pmid, const int* __restrict__ tot,
    int* __restrict__ packed, int* __restrict__ row_start, int* __restrict__ row_end)
{
    __shared__ int bst[NBUCK + 1];
    __shared__ int part[256];
    __shared__ int cnt[BNODES];
    __shared__ int scan_s[BNODES];
    int b = blockIdx.x, t = threadIdx.x;
    build_bstart(tot, bst, part, t);
    int beg = bst[b], end = bst[b + 1];
    if (t < BNODES) cnt[t] = 0;
    __syncthreads();
    for (int e = beg + t; e < end; e += 256)
        atomicAdd(&cnt[((unsigned)pmid[e] >> 25) & 127], 1);
    __syncthreads();
    if (t < BNODES) scan_s[t] = cnt[t];
    __syncthreads();
    for (int off = 1; off < BNODES; off <<= 1) {
        int add = (t >= off && t < BNODES) ? scan_s[t - off] : 0;
        __syncthreads();
        if (t < BNODES) scan_s[t] += add;
        __syncthreads();
    }
    if (t < BNODES) {
        int c = cnt[t];
        int excl = scan_s[t] - c;          // exclusive within bucket
        int node = b * BNODES + t;
        if (node < N_NODES) {
            row_start[node] = beg + excl;
            row_end[node] = beg + excl + c;
        }
        cnt[t] = beg + excl;               // reuse as cursor
    }
    __syncthreads();
    for (int e = beg + t; e < end; e += 256) {
        int p = pmid[e];
        int pos = atomicAdd(&cnt[((unsigned)p >> 25) & 127], 1);
        packed[pos] = p & 0x1FFFFFF;       // src | catx<<16
    }
}

// per-edge load bundle
struct EdgeLd { uint4 kv; float4 t; };
__device__ __forceinline__ float edge_dot(const EdgeLd& e, const float4& q4) {
    float p;
    p = (__uint_as_float(e.kv.x & 0xFFFF0000u) + e.t.x) * q4.x;
    p = fmaf(__uint_as_float(e.kv.y & 0xFFFF0000u) + e.t.y, q4.y, p);
    p = fmaf(__uint_as_float(e.kv.z & 0xFFFF0000u) + e.t.z, q4.z, p);
    p = fmaf(__uint_as_float(e.kv.w & 0xFFFF0000u) + e.t.w, q4.w, p);
    return radd16(p) * SCALE;
}
__device__ __forceinline__ float4 edge_val(const EdgeLd& e) {
    float4 v;
    v.x = __uint_as_float(e.kv.x << 16) + e.t.x;
    v.y = __uint_as_float(e.kv.y << 16) + e.t.y;
    v.z = __uint_as_float(e.kv.z << 16) + e.t.z;
    v.w = __uint_as_float(e.kv.w << 16) + e.t.w;
    return v;
}

// ---------------- fused gather-attention + next-layer qkv GEMM epilogue --------------
// MODE 0: layer 0 — k/v/q from 42-entry global tables (L1-resident), epilogue gemm
// MODE 1: mid layer — global qkv in, epilogue gemm
// MODE 2: last layer — global qkv in, write fp32 h + gate
template<int MODE>
__device__ __forceinline__ void agg_body(
    const int* __restrict__ row_start, const int* __restrict__ row_end,
    const int* __restrict__ packed, const int* __restrict__ x,
    const unsigned* __restrict__ qs_in, const unsigned* __restrict__ kv_in,
    const unsigned* __restrict__ tqs, const unsigned* __restrict__ tkv,
    const float* __restrict__ te,
    const ushort_t* __restrict__ wbn, const float* __restrict__ bqn,
    const float* __restrict__ bkn, const float* __restrict__ bvn,
    const float* __restrict__ bsn,
    unsigned* __restrict__ qs_out, unsigned* __restrict__ kv_out,
    float* __restrict__ hf, const float* __restrict__ gW,
    const float* __restrict__ gb, float* __restrict__ gate,
    float* tel, ushort_t* hs16, int* pkl)
{
    int t = threadIdx.x, bid = blockIdx.x;
    int wave = t >> 6, lane = t & 63;
    int g = lane >> 4, i16 = lane & 15;
    int dst = bid * 16 + wave * 4 + g;
    int beg = row_start[dst], end = row_end[dst];
    int beg0 = row_start[bid * 16];
    int cnt = row_end[bid * 16 + 15] - beg0;
    bool use_lds = (cnt <= PKCAP);
    for (int i = t; i < 640; i += 256) tel[i] = te[i];
    if (use_lds) for (int i = t; i < cnt; i += 256) pkl[i] = packed[beg0 + i];
    uint4 uq;
    if constexpr (MODE == 0)
        uq = *(const uint4*)(tqs + (x[dst] << 6) + (i16 << 2));
    else
        uq = *(const uint4*)(qs_in + (size_t)dst * 64 + (i16 << 2));
    __syncthreads();
    float4 q4, s4;
    q4.x = __uint_as_float(uq.x << 16); s4.x = __uint_as_float(uq.x & 0xFFFF0000u);
    q4.y = __uint_as_float(uq.y << 16); s4.y = __uint_as_float(uq.y & 0xFFFF0000u);
    q4.z = __uint_as_float(uq.z << 16); s4.z = __uint_as_float(uq.z & 0xFFFF0000u);
    q4.w = __uint_as_float(uq.w << 16); s4.w = __uint_as_float(uq.w & 0xFFFF0000u);
    float m = -1e30f, l = 0.f;
    float4 acc = {0.f, 0.f, 0.f, 0.f};

    auto eload = [&](int pkt) {
        EdgeLd r;
        unsigned catx = ((unsigned)pkt >> 16) & 0x1FFu;
        int cat = (int)((catx * 1561u) >> 16);        // catx / 42
        r.t = *(const float4*)(tel + (cat << 6) + (i16 << 2));
        if constexpr (MODE == 0) {
            int xc = (int)catx - cat * NCAT;
            r.kv = *(const uint4*)(tkv + (xc << 6) + (i16 << 2));
        } else {
            int src = pkt & 0xFFFF;
            r.kv = *(const uint4*)(kv_in + ((size_t)src << 6) + (i16 << 2));
        }
        return r;
    };
    auto run = [&](auto PKT) {
        int e = beg;
        for (; e + 3 < end; e += 4) {
            int p0 = PKT(e), p1 = PKT(e + 1), p2 = PKT(e + 2), p3 = PKT(e + 3);
            EdgeLd e0 = eload(p0), e1 = eload(p1), e2 = eload(p2), e3 = eload(p3);
            float a0 = edge_dot(e0, q4), a1 = edge_dot(e1, q4);
            float a2 = edge_dot(e2, q4), a3 = edge_dot(e3, q4);
            float mn = fmaxf(m, fmaxf(fmaxf(a0, a1), fmaxf(a2, a3)));
            float corr = __expf(m - mn);
            float w0 = __expf(a0 - mn), w1 = __expf(a1 - mn);
            float w2 = __expf(a2 - mn), w3 = __expf(a3 - mn);
            float4 v0 = edge_val(e0), v1 = edge_val(e1), v2 = edge_val(e2), v3 = edge_val(e3);
            acc.x = fmaf(w0, v0.x, fmaf(w1, v1.x, fmaf(w2, v2.x, fmaf(w3, v3.x, acc.x * corr))));
            acc.y = fmaf(w0, v0.y, fmaf(w1, v1.y, fmaf(w2, v2.y, fmaf(w3, v3.y, acc.y * corr))));
            acc.z = fmaf(w0, v0.z, fmaf(w1, v1.z, fmaf(w2, v2.z, fmaf(w3, v3.z, acc.z * corr))));
            acc.w = fmaf(w0, v0.w, fmaf(w1, v1.w, fmaf(w2, v2.w, fmaf(w3, v3.w, acc.w * corr))));
            l = fmaf(l, corr, (w0 + w1) + (w2 + w3));
            m = mn;
        }
        for (; e < end; e++) {
            EdgeLd e0 = eload(PKT(e));
            float a = edge_dot(e0, q4);
            float mn = fmaxf(m, a);
            float corr = __expf(m - mn);
            float w = __expf(a - mn);
            float4 v4 = edge_val(e0);
            acc.x = fmaf(w, v4.x, acc.x * corr);
            acc.y = fmaf(w, v4.y, acc.y * corr);
            acc.z = fmaf(w, v4.z, acc.z * corr);
            acc.w = fmaf(w, v4.w, acc.w * corr);
            l = fmaf(l, corr, w);
            m = mn;
        }
    };
    if (use_lds) run([&](int e) { return pkl[e - beg0]; });
    else         run([&](int e) { return packed[e]; });

    float inv = (l > 0.f) ? 1.f / l : 0.f;
    float4 hv;
    hv.x = fmaxf(acc.x * inv + s4.x, 0.f);
    hv.y = fmaxf(acc.y * inv + s4.y, 0.f);
    hv.z = fmaxf(acc.z * inv + s4.z, 0.f);
    hv.w = fmaxf(acc.w * inv + s4.w, 0.f);
    if constexpr (MODE == 2) {
        *(float4*)(hf + (size_t)dst * H + (i16 << 2)) = hv;
        float4 g4 = *(const float4*)(gW + (i16 << 2));
        float p = hv.x * g4.x + hv.y * g4.y + hv.z * g4.z + hv.w * g4.w;
        p = radd16(p);
        if (i16 == 0) gate[dst] = p + gb[0];
    } else {
        // stage the block's 16 fresh h rows as bf16, then 8 MFMA/wave -> next qkv
        uint2 hp;
        hp.x = f2bf(hv.x) | (f2bf(hv.y) << 16);
        hp.y = f2bf(hv.z) | (f2bf(hv.w) << 16);
        *(uint2*)(hs16 + (((wave * 4 + g) << 6) + (i16 << 2))) = hp;
        __syncthreads();
        int n16 = lane & 15, quad = lane >> 4;
        f32x4 oacc[4];
        #pragma unroll
        for (int i = 0; i < 4; i++) oacc[i] = (f32x4){0.f, 0.f, 0.f, 0.f};
        #pragma unroll
        for (int kb = 0; kb < 2; kb++) {
            bf16x8 afr = *(const bf16x8*)(hs16 + ((n16 << 6) + kb * 32 + quad * 8));
            #pragma unroll
            for (int mat = 0; mat < 4; mat++) {
                int ct = mat * 4 + wave;
                const bf16x8* bp = (const bf16x8*)(wbn + (((kb * 4 + quad) << 11) + ((ct * 16 + n16) << 3)));
                oacc[mat] = __builtin_amdgcn_mfma_f32_16x16x32_bf16(afr, *bp, oacc[mat], 0, 0, 0);
            }
        }
        int col = (wave << 4) + n16;
        float bQ = bqn[col], bK = bkn[col], bV = bvn[col], bS = bsn[col];
        int nb = bid * 16 + quad * 4;
        #pragma unroll
        for (int r = 0; r < 4; r++) {
            qs_out[(size_t)(nb + r) * 64 + col] = f2bf(oacc[0][r] + bQ) | (f2bf(oacc[3][r] + bS) << 16);
            kv_out[(size_t)(nb + r) * 64 + col] = f2bf(oacc[2][r] + bV) | (f2bf(oacc[1][r] + bK) << 16);
        }
    }
}

__global__ __launch_bounds__(256, 6) void k_agg0(
    const int* __restrict__ row_start, const int* __restrict__ row_end,
    const int* __restrict__ packed, const int* __restrict__ x,
    const unsigned* __restrict__ tqs, const unsigned* __restrict__ tkv,
    const float* __restrict__ te,
    const ushort_t* __restrict__ wbn, const float* __restrict__ bqn,
    const float* __restrict__ bkn, const float* __restrict__ bvn,
    const float* __restrict__ bsn,
    unsigned* __restrict__ qs_out, unsigned* __restrict__ kv_out)
{
    __shared__ float tel[640];
    __shared__ ushort_t hs16[1024];
    __shared__ int pkl[PKCAP];
    agg_body<0>(row_start, row_end, packed, x, nullptr, nullptr, tqs, tkv, te,
                wbn, bqn, bkn, bvn, bsn, qs_out, kv_out,
                nullptr, nullptr, nullptr, nullptr, tel, hs16, pkl);
}

__global__ __launch_bounds__(256, 6) void k_agg1(
    const int* __restrict__ row_start, const int* __restrict__ row_end,
    const int* __restrict__ packed,
    const unsigned* __restrict__ qs_in, const unsigned* __restrict__ kv_in,
    const float* __restrict__ te,
    const ushort_t* __restrict__ wbn, const float* __restrict__ bqn,
    const float* __restrict__ bkn, const float* __restrict__ bvn,
    const float* __restrict__ bsn,
    unsigned* __restrict__ qs_out, unsigned* __restrict__ kv_out)
{
    __shared__ float tel[640];
    __shared__ ushort_t hs16[1024];
    __shared__ int pkl[PKCAP];
    agg_body<1>(row_start, row_end, packed, nullptr, qs_in, kv_in, nullptr, nullptr, te,
                wbn, bqn, bkn, bvn, bsn, qs_out, kv_out,
                nullptr, nullptr, nullptr, nullptr, tel, hs16, pkl);
}

__global__ __launch_bounds__(256, 6) void k_agg2(
    const int* __restrict__ row_start, const int* __restrict__ row_end,
    const int* __restrict__ packed,
    const unsigned* __restrict__ qs_in, const unsigned* __restrict__ kv_in,
    const float* __restrict__ te,
    float* __restrict__ hf, const float* __restrict__ gW,
    const float* __restrict__ gb, float* __restrict__ gate)
{
    __shared__ float tel[640];
    __shared__ int pkl[PKCAP];
    agg_body<2>(row_start, row_end, packed, nullptr, qs_in, kv_in, nullptr, nullptr, te,
                nullptr, nullptr, nullptr, nullptr, nullptr, nullptr, nullptr,
                hf, gW, gb, gate, tel, nullptr, pkl);
}

// ---------------- fused per-graph readout (W column in registers) ----------------
__global__ __launch_bounds__(256) void k_readout2(
    const float* __restrict__ h, const float* __restrict__ oW,
    const float* __restrict__ ob, const float* __restrict__ gate,
    const int* __restrict__ gs, float* __restrict__ out)
{
    __shared__ float hs[8][H + 1];
    __shared__ float red[256];
    __shared__ float den_s[8];
    __shared__ float gmax_s, den_tot;
    int t = threadIdx.x;
    int g = blockIdx.x;
    int ln = t >> 5, o = t & 31;
    float wreg[H];
    #pragma unroll
    for (int i = 0; i < H; i++) wreg[i] = oW[i * OUTD + o];
    int beg = gs[g], end = gs[g + 1];
    float mx = -INFINITY;
    for (int n = beg + t; n < end; n += 256) mx = fmaxf(mx, gate[n]);
    red[t] = mx;
    __syncthreads();
    for (int sft = 128; sft > 0; sft >>= 1) {
        if (t < sft) red[t] = fmaxf(red[t], red[t + sft]);
        __syncthreads();
    }
    if (t == 0) gmax_s = red[0];
    __syncthreads();
    float gm = gmax_s;
    float acc = 0.f, den = 0.f;
    for (int n0 = beg; n0 < end; n0 += 8) {
        __syncthreads();
        for (int i = t; i < 8 * H; i += 256) {
            int r = i >> 6, c = i & 63;
            int n = n0 + r;
            hs[r][c] = (n < end) ? h[(size_t)n * H + c] : 0.f;
        }
        __syncthreads();
        int n = n0 + ln;
        if (n < end) {
            float wt = __expf(gate[n] - gm);
            float d0 = 0.f;
            #pragma unroll
            for (int i = 0; i < H; i++) d0 += hs[ln][i] * wreg[i];
            acc += wt * d0;
            if (o == 0) den += wt;
        }
    }
    __syncthreads();
    red[t] = acc;
    if (o == 0) den_s[ln] = den;
    __syncthreads();
    for (int sft = 4; sft >= 1; sft >>= 1) {
        if (ln < sft) red[t] += red[t + sft * 32];
        __syncthreads();
    }
    if (t == 0) {
        float dt = 0.f;
        #pragma unroll
        for (int i = 0; i < 8; i++) dt += den_s[i];
        den_tot = dt;
    }
    __syncthreads();
    if (ln == 0) {
        float dt = den_tot;
        out[g * OUTD + o] = (dt > 0.f) ? red[o] / dt + ob[o] : 0.f;
    }
}

extern "C" void kernel_launch(void* const* d_in, const int* in_sizes, int n_in,
                              void* d_out, int out_size, void* d_ws, size_t ws_size,
                              hipStream_t stream)
{
    const int* x        = (const int*)d_in[0];
    const int* ei       = (const int*)d_in[1];
    const int* ea       = (const int*)d_in[2];
    const int* batch    = (const int*)d_in[3];
    const float* node_emb = (const float*)d_in[4];
    const float* edge_emb = (const float*)d_in[5];
    const float* Wq    = (const float*)d_in[6];
    const float* Wk    = (const float*)d_in[7];
    const float* Wv    = (const float*)d_in[8];
    const float* We    = (const float*)d_in[9];
    const float* Wskip = (const float*)d_in[10];
    const float* bq    = (const float*)d_in[11];
    const float* bk    = (const float*)d_in[12];
    const float* bv    = (const float*)d_in[13];
    const float* bskip = (const float*)d_in[14];
    const float* gate_W = (const float*)d_in[15];
    const float* gate_b = (const float*)d_in[16];
    const float* out_W  = (const float*)d_in[17];
    const float* out_b  = (const float*)d_in[18];
    float* out = (float*)d_out;

    const size_t NH = (size_t)N_NODES * H;       // 3,200,000
    float* ws   = (float*)d_ws;
    unsigned* qs_a = (unsigned*)ws;              // layer-1 qkv (written by agg0)
    unsigned* kv_a = qs_a + NH;
    unsigned* qs_b = kv_a + NH;                  // layer-2 qkv (written by agg1)
    unsigned* kv_b = qs_b + NH;
    float* hf32 = (float*)(kv_b + NH);           // fp32 h (final layer only)
    float* te   = hf32 + NH;                     // LAYERS*10*64 = 1920
    float* gate = te + LAYERS * 10 * H;
    int* row_start = (int*)(gate + N_NODES);
    int* row_end   = row_start + N_NODES;
    int* packed    = row_end + N_NODES;          // final CSR edge packets
    int* pmid      = packed + N_EDGES;           // bucket-sorted intermediate
    int* hist      = pmid + N_EDGES;             // NBUCK * NB_HISTB ([bucket][block])
    int* tot       = hist + NBUCK * NB_HISTB;    // NBUCK bucket totals
    int* gs        = tot + NBUCK;                // 257 ints
    unsigned* tqs  = (unsigned*)(gs + NGRAPH + 1);   // 42*64 layer-0 q|s table
    unsigned* tkv  = tqs + FB_TAB * 64;              // 42*64 layer-0 v|k table
    ushort_t* wb16 = (ushort_t*)(tkv + FB_TAB * 64); // 3*16384 bf16 weights (chunk-major)

    k_front<<<NB_FRONT, 256, 0, stream>>>(x, node_emb, edge_emb, We, te, ei, hist, batch, gs,
                                          Wq, Wk, Wv, Wskip, bq, bk, bv, bskip, wb16, tqs, tkv);
    k_scan<<<NB_SCAN, 256, 0, stream>>>(hist, tot);
    k_scatter<<<NB_HISTB, 256, 0, stream>>>(ei, ea, x, hist, tot, pmid);
    k_final<<<NBUCK, 256, 0, stream>>>(pmid, tot, packed, row_start, row_end);

    // layer 0: table-based input, epilogue gemm (wb layer 1) -> A
    k_agg0<<<NB_AGG, 256, 0, stream>>>(
        row_start, row_end, packed, x, tqs, tkv, te,
        wb16 + (size_t)1 * 16384, bq + H, bk + H, bv + H, bskip + H, qs_a, kv_a);
    // layer 1: read A, epilogue gemm (wb layer 2) -> B
    k_agg1<<<NB_AGG, 256, 0, stream>>>(
        row_start, row_end, packed, qs_a, kv_a, te + 10 * H,
        wb16 + (size_t)2 * 16384, bq + 2 * H, bk + 2 * H, bv + 2 * H, bskip + 2 * H, qs_b, kv_b);
    // layer 2: read B, write fp32 h + gate
    k_agg2<<<NB_AGG, 256, 0, stream>>>(
        row_start, row_end, packed, qs_b, kv_b, te + 2 * 10 * H,
        hf32, gate_W, gate_b, gate);

    k_readout2<<<NGRAPH, 256, 0, stream>>>(hf32, out_W, out_b, gate, gs, out);
}